// Round 1
// baseline (8921.545 us; speedup 1.0000x reference)
//
#include <hip/hip_runtime.h>
#include <math.h>

#define DD 1024
#define SS 4096
#define AP 128
#define LN_EPS 1e-6f

// out[n,d] = sum_k A[n,k]*W[d,k]  (+ epilogue)
// MODE 0: plain; 1: + res[n,d]; 2: relu(+ bias[d])
template<int MODE>
__global__ __launch_bounds__(256) void gemm_nt(const float* __restrict__ A,
                                               const float* __restrict__ W,
                                               float* __restrict__ out,
                                               const float* __restrict__ aux) {
    __shared__ float As[64][36];
    __shared__ float Bs[64][36];
    const int tid = threadIdx.x;
    const int m0 = blockIdx.y * 64;
    const int n0 = blockIdx.x * 64;
    const int tx = tid & 15, ty = tid >> 4;
    float acc[4][4] = {};
    for (int kt = 0; kt < DD; kt += 32) {
#pragma unroll
        for (int q = 0; q < 2; q++) {
            const int f = (tid + q * 256) * 4;
            const int r = f >> 5;
            const int c = f & 31;
            *(float4*)(&As[r][c]) = *(const float4*)(A + (size_t)(m0 + r) * DD + kt + c);
            *(float4*)(&Bs[r][c]) = *(const float4*)(W + (size_t)(n0 + r) * DD + kt + c);
        }
        __syncthreads();
#pragma unroll
        for (int kk = 0; kk < 32; kk++) {
            float a[4], b[4];
#pragma unroll
            for (int i = 0; i < 4; i++) a[i] = As[ty * 4 + i][kk];
#pragma unroll
            for (int j = 0; j < 4; j++) b[j] = Bs[tx * 4 + j][kk];
#pragma unroll
            for (int i = 0; i < 4; i++)
#pragma unroll
                for (int j = 0; j < 4; j++) acc[i][j] += a[i] * b[j];
        }
        __syncthreads();
    }
#pragma unroll
    for (int i = 0; i < 4; i++) {
        const int m = m0 + ty * 4 + i;
        const size_t idx = (size_t)m * DD + n0 + tx * 4;
        float4 v = make_float4(acc[i][0], acc[i][1], acc[i][2], acc[i][3]);
        if (MODE == 1) {
            const float4 r4 = *(const float4*)(aux + idx);
            v.x += r4.x; v.y += r4.y; v.z += r4.z; v.w += r4.w;
        }
        if (MODE == 2) {
            const float4 b4 = *(const float4*)(aux + n0 + tx * 4);
            v.x = fmaxf(v.x + b4.x, 0.f);
            v.y = fmaxf(v.y + b4.y, 0.f);
            v.z = fmaxf(v.z + b4.z, 0.f);
            v.w = fmaxf(v.w + b4.w, 0.f);
        }
        *(float4*)(out + idx) = v;
    }
}

// one block (256 thr = 4 waves) per query row; banded window |j-i|<=AP, j!=i
__global__ __launch_bounds__(256) void attn_banded(const float* __restrict__ Q,
                                                   const float* __restrict__ Km,
                                                   const float* __restrict__ V,
                                                   float* __restrict__ C) {
    __shared__ float qs[DD];
    __shared__ float es[2 * AP + 1];
    __shared__ float red[256];
    const int r = blockIdx.x;
    const int b = r / SS;
    const int i = r % SS;
    const int tid = threadIdx.x;
    const int lane = tid & 63;
    const int wave = tid >> 6;
    const float scale = 0.03125f;  // 1/sqrt(1024)
#pragma unroll
    for (int t = 0; t < DD / 256; t++) qs[tid + t * 256] = Q[(size_t)r * DD + tid + t * 256];
    __syncthreads();
    const int j0 = max(0, i - AP);
    const int j1 = min(SS - 1, i + AP);
    const int nj = j1 - j0 + 1;
    const float* Kb = Km + (size_t)b * SS * DD;
    for (int jj = wave; jj < nj; jj += 4) {
        const int j = j0 + jj;
        const float* krow = Kb + (size_t)j * DD;
        float p = 0.f;
#pragma unroll
        for (int t = 0; t < DD / 64; t++) p += qs[lane + t * 64] * krow[lane + t * 64];
#pragma unroll
        for (int off = 32; off > 0; off >>= 1) p += __shfl_down(p, off);
        if (lane == 0) es[jj] = (j == i) ? -INFINITY : p * scale;
    }
    __syncthreads();
    // block max
    float m = -INFINITY;
    for (int jj = tid; jj < nj; jj += 256) m = fmaxf(m, es[jj]);
    red[tid] = m;
    __syncthreads();
    for (int s = 128; s > 0; s >>= 1) {
        if (tid < s) red[tid] = fmaxf(red[tid], red[tid + s]);
        __syncthreads();
    }
    m = red[0];
    __syncthreads();
    // exp + block sum
    float ssum = 0.f;
    for (int jj = tid; jj < nj; jj += 256) {
        const float v = __expf(es[jj] - m);
        es[jj] = v;
        ssum += v;
    }
    red[tid] = ssum;
    __syncthreads();
    for (int s = 128; s > 0; s >>= 1) {
        if (tid < s) red[tid] += red[tid + s];
        __syncthreads();
    }
    const float inv = 1.f / red[0];
    // c[r] = sum_j alpha_j * V[j]
    const float* Vb = V + (size_t)b * SS * DD;
    const int d0 = tid * 4;
    float4 acc = make_float4(0.f, 0.f, 0.f, 0.f);
    for (int jj = 0; jj < nj; jj++) {
        const float w = es[jj];
        const float4 v4 = *(const float4*)(Vb + (size_t)(j0 + jj) * DD + d0);
        acc.x += w * v4.x; acc.y += w * v4.y; acc.z += w * v4.z; acc.w += w * v4.w;
    }
    acc.x *= inv; acc.y *= inv; acc.z *= inv; acc.w *= inv;
    *(float4*)(C + (size_t)r * DD + d0) = acc;
}

__global__ __launch_bounds__(256) void ln_rows(const float* __restrict__ X,
                                               float* __restrict__ Y,
                                               const float* __restrict__ g,
                                               const float* __restrict__ bta) {
    __shared__ float red[256], red2[256];
    const int r = blockIdx.x, tid = threadIdx.x;
    const float4 v = *(const float4*)(X + (size_t)r * DD + tid * 4);
    red[tid] = v.x + v.y + v.z + v.w;
    red2[tid] = v.x * v.x + v.y * v.y + v.z * v.z + v.w * v.w;
    __syncthreads();
    for (int s = 128; s > 0; s >>= 1) {
        if (tid < s) { red[tid] += red[tid + s]; red2[tid] += red2[tid + s]; }
        __syncthreads();
    }
    const float mu = red[0] * (1.f / DD);
    const float var = red2[0] * (1.f / DD) - mu * mu;
    const float rstd = rsqrtf(var + LN_EPS);
    const float4 g4 = *(const float4*)(g + tid * 4);
    const float4 b4 = *(const float4*)(bta + tid * 4);
    float4 o;
    o.x = (v.x - mu) * rstd * g4.x + b4.x;
    o.y = (v.y - mu) * rstd * g4.y + b4.y;
    o.z = (v.z - mu) * rstd * g4.z + b4.z;
    o.w = (v.w - mu) * rstd * g4.w + b4.w;
    *(float4*)(Y + (size_t)r * DD + tid * 4) = o;
}

__global__ __launch_bounds__(256) void k2_head(const float* __restrict__ H,
                                               const float* __restrict__ w2,
                                               const float* __restrict__ b2,
                                               float* __restrict__ out) {
    __shared__ float ws[DD];
    const int tid = threadIdx.x;
#pragma unroll
    for (int t = 0; t < 4; t++) ws[tid + t * 256] = w2[tid + t * 256];
    __syncthreads();
    const int lane = tid & 63, wave = tid >> 6;
    const int r = blockIdx.x * 4 + wave;
    const float* h = H + (size_t)r * DD;
    float p = 0.f;
#pragma unroll
    for (int t = 0; t < 16; t++) p += h[lane + t * 64] * ws[lane + t * 64];
#pragma unroll
    for (int off = 32; off > 0; off >>= 1) p += __shfl_down(p, off);
    if (lane == 0) {
        const float z = p + b2[0];
        out[r] = 1.f / (1.f + __expf(-z));
    }
}

extern "C" void kernel_launch(void* const* d_in, const int* in_sizes, int n_in,
                              void* d_out, int out_size, void* d_ws, size_t ws_size,
                              hipStream_t stream) {
    const float* x   = (const float*)d_in[0];
    const float* Wq  = (const float*)d_in[1];
    const float* Wk  = (const float*)d_in[2];
    const float* Wv  = (const float*)d_in[3];
    const float* Wo  = (const float*)d_in[4];
    const float* k1w = (const float*)d_in[5];
    const float* k1b = (const float*)d_in[6];
    const float* k2w = (const float*)d_in[7];
    const float* k2b = (const float*)d_in[8];
    const float* lng = (const float*)d_in[9];
    const float* lnb = (const float*)d_in[10];
    float* out = (float*)d_out;

    const int N = 4 * SS;  // 16384 rows
    const size_t BUF = (size_t)N * DD;
    float* Q = (float*)d_ws;
    float* K = Q + BUF;
    float* V = K + BUF;
    float* C = V + BUF;
    // buffer reuse for the tail: T->Q, Y->K, H0->V, H->C

    dim3 tb(256);
    dim3 gg(DD / 64, N / 64);

    gemm_nt<0><<<gg, tb, 0, stream>>>(x, Wq, Q, nullptr);
    gemm_nt<0><<<gg, tb, 0, stream>>>(x, Wk, K, nullptr);
    gemm_nt<0><<<gg, tb, 0, stream>>>(x, Wv, V, nullptr);

    attn_banded<<<N, tb, 0, stream>>>(Q, K, V, C);

    gemm_nt<1><<<gg, tb, 0, stream>>>(C, Wo, Q, x);      // T = C@Wo^T + x   (into dead Q)
    ln_rows<<<N, tb, 0, stream>>>(Q, K, lng, lnb);        // Y = LN(T)       (into dead K)
    gemm_nt<2><<<gg, tb, 0, stream>>>(K, k1w, V, k1b);    // H0 = relu(Y@k1^T + b) (into dead V)
    ln_rows<<<N, tb, 0, stream>>>(V, C, lng, lnb);        // H = LN(H0)      (into dead C)
    k2_head<<<N / 4, tb, 0, stream>>>(C, k2w, k2b, out);  // out = sigmoid(H@k2 + b)
}

// Round 2
// 1217.006 us; speedup vs baseline: 7.3307x; 7.3307x over previous
//
#include <hip/hip_runtime.h>
#include <math.h>

#define DD 1024
#define SS 4096
#define AP 128
#define LN_EPS 1e-6f
#define BM 128
#define BN 128
#define BK 32

typedef __bf16 bf16;
typedef __attribute__((ext_vector_type(4))) __bf16 bf16x4;
typedef __attribute__((ext_vector_type(8))) __bf16 bf16x8;
typedef __attribute__((ext_vector_type(4))) float f32x4;

#define GLOAD_LDS16(g, l)                                                   \
    __builtin_amdgcn_global_load_lds(                                        \
        (const __attribute__((address_space(1))) void*)(g),                  \
        (__attribute__((address_space(3))) void*)(l), 16, 0, 0)

// ---------------- casts ----------------
__global__ __launch_bounds__(256) void cast_f2b(const float* __restrict__ s,
                                                bf16* __restrict__ d) {
    const int i = (blockIdx.x * 256 + threadIdx.x) * 4;
    const float4 a = *(const float4*)(s + i);
    bf16x4 o;
    o[0] = (__bf16)a.x; o[1] = (__bf16)a.y; o[2] = (__bf16)a.z; o[3] = (__bf16)a.w;
    *(bf16x4*)(d + i) = o;
}

__global__ __launch_bounds__(256) void cast5_f2b(const float* __restrict__ w0,
                                                 const float* __restrict__ w1,
                                                 const float* __restrict__ w2,
                                                 const float* __restrict__ w3,
                                                 const float* __restrict__ w4,
                                                 bf16* __restrict__ d) {
    const float* s;
    switch (blockIdx.y) {
        case 0: s = w0; break;
        case 1: s = w1; break;
        case 2: s = w2; break;
        case 3: s = w3; break;
        default: s = w4; break;
    }
    const int i = (blockIdx.x * 256 + threadIdx.x) * 4;
    const float4 a = *(const float4*)(s + i);
    bf16x4 o;
    o[0] = (__bf16)a.x; o[1] = (__bf16)a.y; o[2] = (__bf16)a.z; o[3] = (__bf16)a.w;
    *(bf16x4*)(d + ((size_t)blockIdx.y << 20) + i) = o;
}

// ---------------- bf16 MFMA GEMM: out[m,n] = sum_k A[m,k]*W[n,k] ----------------
// MODE 0: bf16 out; MODE 1: f32 out + aux[m,n] residual; MODE 2: f32 relu(out + aux[n])
template<int MODE>
__global__ __launch_bounds__(256) void gemm_bt_mfma(const bf16* __restrict__ A,
                                                    const bf16* __restrict__ W,
                                                    float* __restrict__ out,
                                                    bf16* __restrict__ outb,
                                                    const float* __restrict__ aux) {
    __shared__ bf16 As[BM * BK];  // row-major [128][32], unpadded (global_load_lds)
    __shared__ bf16 Bs[BN * BK];
    const int tid = threadIdx.x;
    const int lane = tid & 63;
    const int wave = tid >> 6;
    const int wm = wave & 1;   // wave grid 2x2, each wave does 64x64
    const int wn = wave >> 1;
    const int m0 = blockIdx.y * BM;
    const int n0 = blockIdx.x * BN;

    // staging chunk: c covers LDS bytes [c*16, c*16+16) == elements [c*8, c*8+8)
    const int c = wave * 64 + lane;
    const int ar = c >> 2;          // tile row
    const int ac = (c & 3) << 3;    // k offset within tile
    char* AsB = (char*)As;
    char* BsB = (char*)Bs;

    const int lr = lane & 15;         // fragment row (m or n)
    const int lk = (lane >> 4) << 3;  // fragment k offset

    f32x4 acc[4][4] = {};

    for (int kt = 0; kt < DD; kt += BK) {
        const bf16* ga0 = A + (size_t)(m0 + ar) * DD + kt + ac;
        const bf16* gb0 = W + (size_t)(n0 + ar) * DD + kt + ac;
        GLOAD_LDS16(ga0, AsB + wave * 1024);
        GLOAD_LDS16(ga0 + (size_t)64 * DD, AsB + 4096 + wave * 1024);
        GLOAD_LDS16(gb0, BsB + wave * 1024);
        GLOAD_LDS16(gb0 + (size_t)64 * DD, BsB + 4096 + wave * 1024);
        __syncthreads();

        bf16x8 af[4], bf[4];
#pragma unroll
        for (int i = 0; i < 4; i++)
            af[i] = *(const bf16x8*)&As[(wm * 64 + i * 16 + lr) * BK + lk];
#pragma unroll
        for (int j = 0; j < 4; j++)
            bf[j] = *(const bf16x8*)&Bs[(wn * 64 + j * 16 + lr) * BK + lk];
#pragma unroll
        for (int i = 0; i < 4; i++)
#pragma unroll
            for (int j = 0; j < 4; j++)
                acc[i][j] = __builtin_amdgcn_mfma_f32_16x16x32_bf16(af[i], bf[j], acc[i][j], 0, 0, 0);
        __syncthreads();
    }

    // C/D layout: col = lane&15, row = (lane>>4)*4 + reg
#pragma unroll
    for (int i = 0; i < 4; i++) {
        const int row = m0 + wm * 64 + i * 16 + ((lane >> 4) << 2);
#pragma unroll
        for (int j = 0; j < 4; j++) {
            const int col = n0 + wn * 64 + j * 16 + (lane & 15);
#pragma unroll
            for (int rr = 0; rr < 4; rr++) {
                const size_t idx = (size_t)(row + rr) * DD + col;
                const float v = acc[i][j][rr];
                if (MODE == 0) outb[idx] = (__bf16)v;
                if (MODE == 1) out[idx] = v + aux[idx];
                if (MODE == 2) out[idx] = fmaxf(v + aux[col], 0.f);
            }
        }
    }
}

// ---------------- banded attention, one block per query row, bf16 QKV ----------------
__global__ __launch_bounds__(256) void attn_banded(const bf16* __restrict__ Q,
                                                   const bf16* __restrict__ Km,
                                                   const bf16* __restrict__ V,
                                                   bf16* __restrict__ C) {
    __shared__ float es[2 * AP + 1];
    __shared__ float red[256];
    const int r = blockIdx.x;
    const int b = r / SS;
    const int i = r % SS;
    const int tid = threadIdx.x;
    const int lane = tid & 63;
    const int wave = tid >> 6;
    const float scale = 0.03125f;  // 1/sqrt(1024)

    // each lane caches its 16 contiguous q elems in registers
    float qf[16];
    {
        const bf16* qrow = Q + (size_t)r * DD + lane * 16;
        const bf16x8 q0 = *(const bf16x8*)(qrow);
        const bf16x8 q1 = *(const bf16x8*)(qrow + 8);
#pragma unroll
        for (int e = 0; e < 8; e++) { qf[e] = (float)q0[e]; qf[8 + e] = (float)q1[e]; }
    }

    const int j0 = max(0, i - AP);
    const int j1 = min(SS - 1, i + AP);
    const int nj = j1 - j0 + 1;
    const bf16* Kb = Km + (size_t)b * SS * DD;

    for (int jj = wave; jj < nj; jj += 4) {
        const int j = j0 + jj;
        const bf16* krow = Kb + (size_t)j * DD + lane * 16;
        const bf16x8 k0 = *(const bf16x8*)(krow);
        const bf16x8 k1 = *(const bf16x8*)(krow + 8);
        float p = 0.f;
#pragma unroll
        for (int e = 0; e < 8; e++) p += qf[e] * (float)k0[e];
#pragma unroll
        for (int e = 0; e < 8; e++) p += qf[8 + e] * (float)k1[e];
#pragma unroll
        for (int off = 32; off > 0; off >>= 1) p += __shfl_down(p, off);
        if (lane == 0) es[jj] = (j == i) ? -INFINITY : p * scale;
    }
    __syncthreads();
    float m = -INFINITY;
    for (int jj = tid; jj < nj; jj += 256) m = fmaxf(m, es[jj]);
    red[tid] = m;
    __syncthreads();
    for (int s = 128; s > 0; s >>= 1) {
        if (tid < s) red[tid] = fmaxf(red[tid], red[tid + s]);
        __syncthreads();
    }
    m = red[0];
    __syncthreads();
    float ssum = 0.f;
    for (int jj = tid; jj < nj; jj += 256) {
        const float v = __expf(es[jj] - m);
        es[jj] = v;
        ssum += v;
    }
    red[tid] = ssum;
    __syncthreads();
    for (int s = 128; s > 0; s >>= 1) {
        if (tid < s) red[tid] += red[tid + s];
        __syncthreads();
    }
    const float inv = 1.f / red[0];

    const bf16* Vb = V + (size_t)b * SS * DD;
    const int d0 = tid * 4;
    float4 acc = make_float4(0.f, 0.f, 0.f, 0.f);
    for (int jj = 0; jj < nj; jj++) {
        const float w = es[jj];
        const bf16x4 v4 = *(const bf16x4*)(Vb + (size_t)(j0 + jj) * DD + d0);
        acc.x += w * (float)v4[0];
        acc.y += w * (float)v4[1];
        acc.z += w * (float)v4[2];
        acc.w += w * (float)v4[3];
    }
    bf16x4 o;
    o[0] = (__bf16)(acc.x * inv);
    o[1] = (__bf16)(acc.y * inv);
    o[2] = (__bf16)(acc.z * inv);
    o[3] = (__bf16)(acc.w * inv);
    *(bf16x4*)(C + (size_t)r * DD + d0) = o;
}

// ---------------- layernorm over rows of 1024; OUT_BF selects output dtype ----------------
template<bool OUT_BF>
__global__ __launch_bounds__(256) void ln_rows(const float* __restrict__ X,
                                               float* __restrict__ Yf,
                                               bf16* __restrict__ Yb,
                                               const float* __restrict__ g,
                                               const float* __restrict__ bta) {
    __shared__ float red[256], red2[256];
    const int r = blockIdx.x, tid = threadIdx.x;
    const float4 v = *(const float4*)(X + (size_t)r * DD + tid * 4);
    red[tid] = v.x + v.y + v.z + v.w;
    red2[tid] = v.x * v.x + v.y * v.y + v.z * v.z + v.w * v.w;
    __syncthreads();
    for (int s = 128; s > 0; s >>= 1) {
        if (tid < s) { red[tid] += red[tid + s]; red2[tid] += red2[tid + s]; }
        __syncthreads();
    }
    const float mu = red[0] * (1.f / DD);
    const float var = red2[0] * (1.f / DD) - mu * mu;
    const float rstd = rsqrtf(var + LN_EPS);
    const float4 g4 = *(const float4*)(g + tid * 4);
    const float4 b4 = *(const float4*)(bta + tid * 4);
    float4 o;
    o.x = (v.x - mu) * rstd * g4.x + b4.x;
    o.y = (v.y - mu) * rstd * g4.y + b4.y;
    o.z = (v.z - mu) * rstd * g4.z + b4.z;
    o.w = (v.w - mu) * rstd * g4.w + b4.w;
    if (OUT_BF) {
        bf16x4 ob;
        ob[0] = (__bf16)o.x; ob[1] = (__bf16)o.y; ob[2] = (__bf16)o.z; ob[3] = (__bf16)o.w;
        *(bf16x4*)(Yb + (size_t)r * DD + tid * 4) = ob;
    } else {
        *(float4*)(Yf + (size_t)r * DD + tid * 4) = o;
    }
}

__global__ __launch_bounds__(256) void k2_head(const float* __restrict__ H,
                                               const float* __restrict__ w2,
                                               const float* __restrict__ b2,
                                               float* __restrict__ out) {
    __shared__ float ws[DD];
    const int tid = threadIdx.x;
#pragma unroll
    for (int t = 0; t < 4; t++) ws[tid + t * 256] = w2[tid + t * 256];
    __syncthreads();
    const int lane = tid & 63, wave = tid >> 6;
    const int r = blockIdx.x * 4 + wave;
    const float* h = H + (size_t)r * DD;
    float p = 0.f;
#pragma unroll
    for (int t = 0; t < 16; t++) p += h[lane + t * 64] * ws[lane + t * 64];
#pragma unroll
    for (int off = 32; off > 0; off >>= 1) p += __shfl_down(p, off);
    if (lane == 0) {
        const float z = p + b2[0];
        out[r] = 1.f / (1.f + __expf(-z));
    }
}

extern "C" void kernel_launch(void* const* d_in, const int* in_sizes, int n_in,
                              void* d_out, int out_size, void* d_ws, size_t ws_size,
                              hipStream_t stream) {
    const float* x   = (const float*)d_in[0];
    const float* Wq  = (const float*)d_in[1];
    const float* Wk  = (const float*)d_in[2];
    const float* Wv  = (const float*)d_in[3];
    const float* Wo  = (const float*)d_in[4];
    const float* k1w = (const float*)d_in[5];
    const float* k1b = (const float*)d_in[6];
    const float* k2w = (const float*)d_in[7];
    const float* k2b = (const float*)d_in[8];
    const float* lng = (const float*)d_in[9];
    const float* lnb = (const float*)d_in[10];
    float* out = (float*)d_out;

    const int N = 4 * SS;  // 16384 rows
    char* ws = (char*)d_ws;
    bf16* Qb  = (bf16*)(ws);                         // 32MB
    bf16* Kb  = (bf16*)(ws + ((size_t)32 << 20));    // 32MB
    bf16* Vb  = (bf16*)(ws + ((size_t)64 << 20));    // 32MB
    bf16* Cb  = (bf16*)(ws + ((size_t)96 << 20));    // 32MB
    float* T  = (float*)(ws + ((size_t)128 << 20));  // 64MB
    bf16* xb  = (bf16*)(ws + ((size_t)192 << 20));   // 32MB
    bf16* Wqb = (bf16*)(ws + ((size_t)224 << 20));   // 5 x 2MB
    bf16* Wkb = Wqb + (1 << 20);
    bf16* Wvb = Wkb + (1 << 20);
    bf16* Wob = Wvb + (1 << 20);
    bf16* k1wb = Wob + (1 << 20);
    // reuse after liveness ends:
    bf16* Ybf = Qb;                                  // LN1 out (Qb dead after attn)
    float* H0 = (float*)(ws + ((size_t)32 << 20));   // k1 out (over Kb+Vb, dead after attn)
    float* H  = T;                                   // LN2 out (T dead after LN1)

    dim3 tb(256);
    dim3 gg(DD / BN, N / BM);  // (8, 128)

    cast_f2b<<<N * DD / 1024, tb, 0, stream>>>(x, xb);
    cast5_f2b<<<dim3(1024, 5), tb, 0, stream>>>(Wq, Wk, Wv, Wo, k1w, Wqb);

    gemm_bt_mfma<0><<<gg, tb, 0, stream>>>(xb, Wqb, nullptr, Qb, nullptr);
    gemm_bt_mfma<0><<<gg, tb, 0, stream>>>(xb, Wkb, nullptr, Kb, nullptr);
    gemm_bt_mfma<0><<<gg, tb, 0, stream>>>(xb, Wvb, nullptr, Vb, nullptr);

    attn_banded<<<N, tb, 0, stream>>>(Qb, Kb, Vb, Cb);

    gemm_bt_mfma<1><<<gg, tb, 0, stream>>>(Cb, Wob, T, nullptr, x);    // T = C@Wo^T + x
    ln_rows<true><<<N, tb, 0, stream>>>(T, nullptr, Ybf, lng, lnb);     // Ybf = LN(T)
    gemm_bt_mfma<2><<<gg, tb, 0, stream>>>(Ybf, k1wb, H0, nullptr, k1b);// H0 = relu(.+b)
    ln_rows<false><<<N, tb, 0, stream>>>(H0, H, nullptr, lng, lnb);     // H = LN(H0)
    k2_head<<<N / 4, tb, 0, stream>>>(H, k2w, k2b, out);
}

// Round 3
// 556.791 us; speedup vs baseline: 16.0231x; 2.1857x over previous
//
#include <hip/hip_runtime.h>
#include <math.h>

#define DD 1024
#define SS 4096
#define AP 128
#define LN_EPS 1e-6f
#define BM 128
#define BN 128
#define BK 32
#define BAND 384  // 3 x 128 aligned K-tiles cover [t0-128, t0+255]

typedef __bf16 bf16;
typedef __attribute__((ext_vector_type(4))) __bf16 bf16x4;
typedef __attribute__((ext_vector_type(8))) __bf16 bf16x8;
typedef __attribute__((ext_vector_type(4))) float f32x4;

#define GLOAD_LDS16(g, l)                                                   \
    __builtin_amdgcn_global_load_lds(                                        \
        (const __attribute__((address_space(1))) void*)(g),                  \
        (__attribute__((address_space(3))) void*)(l), 16, 0, 0)

// ---------------- casts ----------------
__global__ __launch_bounds__(256) void cast_f2b(const float* __restrict__ s,
                                                bf16* __restrict__ d) {
    const int i = (blockIdx.x * 256 + threadIdx.x) * 4;
    const float4 a = *(const float4*)(s + i);
    bf16x4 o;
    o[0] = (__bf16)a.x; o[1] = (__bf16)a.y; o[2] = (__bf16)a.z; o[3] = (__bf16)a.w;
    *(bf16x4*)(d + i) = o;
}

__global__ __launch_bounds__(256) void cast5_f2b(const float* __restrict__ w0,
                                                 const float* __restrict__ w1,
                                                 const float* __restrict__ w2,
                                                 const float* __restrict__ w3,
                                                 const float* __restrict__ w4,
                                                 bf16* __restrict__ d) {
    const float* s;
    switch (blockIdx.y) {
        case 0: s = w0; break;
        case 1: s = w1; break;
        case 2: s = w2; break;
        case 3: s = w3; break;
        default: s = w4; break;
    }
    const int i = (blockIdx.x * 256 + threadIdx.x) * 4;
    const float4 a = *(const float4*)(s + i);
    bf16x4 o;
    o[0] = (__bf16)a.x; o[1] = (__bf16)a.y; o[2] = (__bf16)a.z; o[3] = (__bf16)a.w;
    *(bf16x4*)(d + ((size_t)blockIdx.y << 20) + i) = o;
}

// ---------------- bf16 MFMA GEMM: out[m,n] = sum_k A[m,k]*W[n,k] ----------------
// MODE 0: bf16 out; MODE 1: f32 out + aux[m,n] residual; MODE 2: f32 relu(out + aux[n])
template<int MODE>
__global__ __launch_bounds__(256) void gemm_proj(const bf16* __restrict__ A,
                                                 const bf16* __restrict__ W,
                                                 float* __restrict__ out,
                                                 bf16* __restrict__ outb,
                                                 const float* __restrict__ aux,
                                                 int ldo) {
    __shared__ bf16 As[BM * BK];
    __shared__ bf16 Bs[BN * BK];
    const int tid = threadIdx.x;
    const int lane = tid & 63;
    const int wave = tid >> 6;
    const int wm = wave & 1;
    const int wn = wave >> 1;
    const int m0 = blockIdx.y * BM;
    const int n0 = blockIdx.x * BN;

    const int c = wave * 64 + lane;
    const int ar = c >> 2;
    const int ac = (c & 3) << 3;
    char* AsB = (char*)As;
    char* BsB = (char*)Bs;
    const int lr = lane & 15;
    const int lk = (lane >> 4) << 3;

    f32x4 acc[4][4] = {};

    for (int kt = 0; kt < DD; kt += BK) {
        const bf16* ga0 = A + (size_t)(m0 + ar) * DD + kt + ac;
        const bf16* gb0 = W + (size_t)(n0 + ar) * DD + kt + ac;
        GLOAD_LDS16(ga0, AsB + wave * 1024);
        GLOAD_LDS16(ga0 + (size_t)64 * DD, AsB + 4096 + wave * 1024);
        GLOAD_LDS16(gb0, BsB + wave * 1024);
        GLOAD_LDS16(gb0 + (size_t)64 * DD, BsB + 4096 + wave * 1024);
        __syncthreads();

        bf16x8 af[4], bfr[4];
#pragma unroll
        for (int i = 0; i < 4; i++)
            af[i] = *(const bf16x8*)&As[(wm * 64 + i * 16 + lr) * BK + lk];
#pragma unroll
        for (int j = 0; j < 4; j++)
            bfr[j] = *(const bf16x8*)&Bs[(wn * 64 + j * 16 + lr) * BK + lk];
#pragma unroll
        for (int i = 0; i < 4; i++)
#pragma unroll
            for (int j = 0; j < 4; j++)
                acc[i][j] = __builtin_amdgcn_mfma_f32_16x16x32_bf16(af[i], bfr[j], acc[i][j], 0, 0, 0);
        __syncthreads();
    }

#pragma unroll
    for (int i = 0; i < 4; i++) {
        const int row = m0 + wm * 64 + i * 16 + ((lane >> 4) << 2);
#pragma unroll
        for (int j = 0; j < 4; j++) {
            const int col = n0 + wn * 64 + j * 16 + (lane & 15);
#pragma unroll
            for (int rr = 0; rr < 4; rr++) {
                const size_t idx = (size_t)(row + rr) * ldo + col;
                const float v = acc[i][j][rr];
                if (MODE == 0) outb[idx] = (__bf16)v;
                if (MODE == 1) out[idx] = v + aux[idx];
                if (MODE == 2) out[idx] = fmaxf(v + aux[col], 0.f);
            }
        }
    }
}

// ---------------- attention pass A1: raw banded scores S = Q @ K_band^T ----------------
// grid (3, 128): nb = which 128-col chunk of the 384 band, t = 128-row Q tile
__global__ __launch_bounds__(256) void attn_s_mfma(const bf16* __restrict__ Q,
                                                   const bf16* __restrict__ K,
                                                   float* __restrict__ S) {
    __shared__ bf16 As[BM * BK];
    __shared__ bf16 Bs[BN * BK];
    const int tid = threadIdx.x;
    const int lane = tid & 63;
    const int wave = tid >> 6;
    const int wm = wave & 1;
    const int wn = wave >> 1;
    const int t = blockIdx.y;
    const int m0 = t * 128;
    const long w0 = (long)t * 128 - 128 + (long)blockIdx.x * 128;  // K row base (signed; OOB lands in adjacent ws buffers, masked in softmax)

    const int c = wave * 64 + lane;
    const int ar = c >> 2;
    const int ac = (c & 3) << 3;
    char* AsB = (char*)As;
    char* BsB = (char*)Bs;
    const int lr = lane & 15;
    const int lk = (lane >> 4) << 3;

    f32x4 acc[4][4] = {};

    for (int kt = 0; kt < DD; kt += BK) {
        const bf16* ga0 = Q + (size_t)(m0 + ar) * DD + kt + ac;
        const bf16* gb0 = K + (w0 + ar) * DD + kt + ac;
        GLOAD_LDS16(ga0, AsB + wave * 1024);
        GLOAD_LDS16(ga0 + (size_t)64 * DD, AsB + 4096 + wave * 1024);
        GLOAD_LDS16(gb0, BsB + wave * 1024);
        GLOAD_LDS16(gb0 + (size_t)64 * DD, BsB + 4096 + wave * 1024);
        __syncthreads();

        bf16x8 af[4], bfr[4];
#pragma unroll
        for (int i = 0; i < 4; i++)
            af[i] = *(const bf16x8*)&As[(wm * 64 + i * 16 + lr) * BK + lk];
#pragma unroll
        for (int j = 0; j < 4; j++)
            bfr[j] = *(const bf16x8*)&Bs[(wn * 64 + j * 16 + lr) * BK + lk];
#pragma unroll
        for (int i = 0; i < 4; i++)
#pragma unroll
            for (int j = 0; j < 4; j++)
                acc[i][j] = __builtin_amdgcn_mfma_f32_16x16x32_bf16(af[i], bfr[j], acc[i][j], 0, 0, 0);
        __syncthreads();
    }

#pragma unroll
    for (int i = 0; i < 4; i++) {
        const int row = m0 + wm * 64 + i * 16 + ((lane >> 4) << 2);
#pragma unroll
        for (int j = 0; j < 4; j++) {
            const int col = blockIdx.x * 128 + wn * 64 + j * 16 + (lane & 15);
#pragma unroll
            for (int rr = 0; rr < 4; rr++)
                S[(size_t)(row + rr) * BAND + col] = acc[i][j][rr];
        }
    }
}

// ---------------- attention pass A2: masked softmax, normalized bf16 P ----------------
// one wave per row; 4096 blocks x 256
__global__ __launch_bounds__(256) void attn_softmax(const float* __restrict__ S,
                                                    bf16* __restrict__ P) {
    const int wave = threadIdx.x >> 6;
    const int lane = threadIdx.x & 63;
    const int g = blockIdx.x * 4 + wave;
    const int i = g & (SS - 1);
    const int j_start = ((i >> 7) << 7) - 128;
    const float scale = 0.03125f;  // 1/sqrt(1024)
    float s[6];
    float m = -INFINITY;
#pragma unroll
    for (int t = 0; t < 6; t++) {
        const int jj = lane + t * 64;
        const int j = j_start + jj;
        const int dj = j - i;
        const bool valid = (j >= 0) && (j < SS) && (dj != 0) && (dj <= AP) && (dj >= -AP);
        const float v = S[(size_t)g * BAND + jj] * scale;
        s[t] = valid ? v : -INFINITY;
        m = fmaxf(m, s[t]);
    }
#pragma unroll
    for (int off = 32; off > 0; off >>= 1) m = fmaxf(m, __shfl_xor(m, off));
    float l = 0.f;
#pragma unroll
    for (int t = 0; t < 6; t++) {
        s[t] = __expf(s[t] - m);
        l += s[t];
    }
#pragma unroll
    for (int off = 32; off > 0; off >>= 1) l += __shfl_xor(l, off);
    const float inv = 1.f / l;
#pragma unroll
    for (int t = 0; t < 6; t++)
        P[(size_t)g * BAND + lane + t * 64] = (__bf16)(s[t] * inv);
}

// ---------------- attention pass B: C = P @ V_band (Vt is V^T, [1024][16384]) ----------------
// grid (8, 128): n0 = 128 D-cols, t = 128-row Q tile; K extent = 384
__global__ __launch_bounds__(256) void attn_pv_mfma(const bf16* __restrict__ P,
                                                    const bf16* __restrict__ Vt,
                                                    bf16* __restrict__ C) {
    __shared__ bf16 As[BM * BK];
    __shared__ bf16 Bs[BN * BK];
    const int tid = threadIdx.x;
    const int lane = tid & 63;
    const int wave = tid >> 6;
    const int wm = wave & 1;
    const int wn = wave >> 1;
    const int t = blockIdx.y;
    const int m0 = t * 128;
    const int n0 = blockIdx.x * 128;
    const bf16* Wb = Vt + (long)t * 128 - 128;  // signed col base into Vt rows

    const int c = wave * 64 + lane;
    const int ar = c >> 2;
    const int ac = (c & 3) << 3;
    char* AsB = (char*)As;
    char* BsB = (char*)Bs;
    const int lr = lane & 15;
    const int lk = (lane >> 4) << 3;

    f32x4 acc[4][4] = {};

    for (int kt = 0; kt < BAND; kt += BK) {
        const bf16* ga0 = P + (size_t)(m0 + ar) * BAND + kt + ac;
        const bf16* gb0 = Wb + (size_t)(n0 + ar) * (4 * SS) + kt + ac;
        GLOAD_LDS16(ga0, AsB + wave * 1024);
        GLOAD_LDS16(ga0 + (size_t)64 * BAND, AsB + 4096 + wave * 1024);
        GLOAD_LDS16(gb0, BsB + wave * 1024);
        GLOAD_LDS16(gb0 + (size_t)64 * (4 * SS), BsB + 4096 + wave * 1024);
        __syncthreads();

        bf16x8 af[4], bfr[4];
#pragma unroll
        for (int i = 0; i < 4; i++)
            af[i] = *(const bf16x8*)&As[(wm * 64 + i * 16 + lr) * BK + lk];
#pragma unroll
        for (int j = 0; j < 4; j++)
            bfr[j] = *(const bf16x8*)&Bs[(wn * 64 + j * 16 + lr) * BK + lk];
#pragma unroll
        for (int i = 0; i < 4; i++)
#pragma unroll
            for (int j = 0; j < 4; j++)
                acc[i][j] = __builtin_amdgcn_mfma_f32_16x16x32_bf16(af[i], bfr[j], acc[i][j], 0, 0, 0);
        __syncthreads();
    }

#pragma unroll
    for (int i = 0; i < 4; i++) {
        const int row = m0 + wm * 64 + i * 16 + ((lane >> 4) << 2);
#pragma unroll
        for (int j = 0; j < 4; j++) {
            const int col = n0 + wn * 64 + j * 16 + (lane & 15);
#pragma unroll
            for (int rr = 0; rr < 4; rr++)
                C[(size_t)(row + rr) * DD + col] = (__bf16)acc[i][j][rr];
        }
    }
}

// ---------------- layernorm over rows of 1024 ----------------
template<bool OUT_BF>
__global__ __launch_bounds__(256) void ln_rows(const float* __restrict__ X,
                                               float* __restrict__ Yf,
                                               bf16* __restrict__ Yb,
                                               const float* __restrict__ g,
                                               const float* __restrict__ bta) {
    __shared__ float red[256], red2[256];
    const int r = blockIdx.x, tid = threadIdx.x;
    const float4 v = *(const float4*)(X + (size_t)r * DD + tid * 4);
    red[tid] = v.x + v.y + v.z + v.w;
    red2[tid] = v.x * v.x + v.y * v.y + v.z * v.z + v.w * v.w;
    __syncthreads();
    for (int s = 128; s > 0; s >>= 1) {
        if (tid < s) { red[tid] += red[tid + s]; red2[tid] += red2[tid + s]; }
        __syncthreads();
    }
    const float mu = red[0] * (1.f / DD);
    const float var = red2[0] * (1.f / DD) - mu * mu;
    const float rstd = rsqrtf(var + LN_EPS);
    const float4 g4 = *(const float4*)(g + tid * 4);
    const float4 b4 = *(const float4*)(bta + tid * 4);
    float4 o;
    o.x = (v.x - mu) * rstd * g4.x + b4.x;
    o.y = (v.y - mu) * rstd * g4.y + b4.y;
    o.z = (v.z - mu) * rstd * g4.z + b4.z;
    o.w = (v.w - mu) * rstd * g4.w + b4.w;
    if (OUT_BF) {
        bf16x4 ob;
        ob[0] = (__bf16)o.x; ob[1] = (__bf16)o.y; ob[2] = (__bf16)o.z; ob[3] = (__bf16)o.w;
        *(bf16x4*)(Yb + (size_t)r * DD + tid * 4) = ob;
    } else {
        *(float4*)(Yf + (size_t)r * DD + tid * 4) = o;
    }
}

__global__ __launch_bounds__(256) void k2_head(const float* __restrict__ H,
                                               const float* __restrict__ w2,
                                               const float* __restrict__ b2,
                                               float* __restrict__ out) {
    __shared__ float ws[DD];
    const int tid = threadIdx.x;
#pragma unroll
    for (int t = 0; t < 4; t++) ws[tid + t * 256] = w2[tid + t * 256];
    __syncthreads();
    const int lane = tid & 63, wave = tid >> 6;
    const int r = blockIdx.x * 4 + wave;
    const float* h = H + (size_t)r * DD;
    float p = 0.f;
#pragma unroll
    for (int t = 0; t < 16; t++) p += h[lane + t * 64] * ws[lane + t * 64];
#pragma unroll
    for (int off = 32; off > 0; off >>= 1) p += __shfl_down(p, off);
    if (lane == 0) {
        const float z = p + b2[0];
        out[r] = 1.f / (1.f + __expf(-z));
    }
}

extern "C" void kernel_launch(void* const* d_in, const int* in_sizes, int n_in,
                              void* d_out, int out_size, void* d_ws, size_t ws_size,
                              hipStream_t stream) {
    const float* x   = (const float*)d_in[0];
    const float* Wq  = (const float*)d_in[1];
    const float* Wk  = (const float*)d_in[2];
    const float* Wv  = (const float*)d_in[3];
    const float* Wo  = (const float*)d_in[4];
    const float* k1w = (const float*)d_in[5];
    const float* k1b = (const float*)d_in[6];
    const float* k2w = (const float*)d_in[7];
    const float* k2b = (const float*)d_in[8];
    const float* lng = (const float*)d_in[9];
    const float* lnb = (const float*)d_in[10];
    float* out = (float*)d_out;

    const int N = 4 * SS;  // 16384 rows
    char* ws = (char*)d_ws;
    // layout (MB offsets). Kb and Vt are deliberately surrounded by valid
    // buffers: band passes read up to 256 KB before/after them (masked to 0).
    bf16*  Qb  = (bf16*)(ws);                          //   0..32
    bf16*  Kb  = (bf16*)(ws + ((size_t)32  << 20));    //  32..64
    bf16*  Vt  = (bf16*)(ws + ((size_t)64  << 20));    //  64..96  [1024][16384]
    bf16*  xb  = (bf16*)(ws + ((size_t)96  << 20));    //  96..128 (dead after Vt gemm)
    float* S   = (float*)(ws + ((size_t)96  << 20));   //  96..120 (over dead xb)
    bf16*  P   = (bf16*)(ws + ((size_t)120 << 20));    // 120..132
    bf16*  Cb  = (bf16*)(ws + ((size_t)132 << 20));    // 132..164
    float* T   = (float*)(ws + ((size_t)164 << 20));   // 164..228
    bf16*  Wqb = (bf16*)(ws + ((size_t)228 << 20));    // 228..238: 5 x 2MB weights
    bf16*  Wkb = Wqb + (1 << 20);
    bf16*  Wvb = Wkb + (1 << 20);
    bf16*  Wob = Wvb + (1 << 20);
    bf16*  k1wb = Wob + (1 << 20);
    // reuse: Ybf over Qb (dead after attn_s); H0 over Kb+Vt (64MB, dead after attn_pv); H over T
    bf16*  Ybf = Qb;
    float* H0  = (float*)(ws + ((size_t)32 << 20));
    float* H   = T;

    dim3 tb(256);
    dim3 gp(DD / BN, N / BM);   // (8, 128) proj gemms

    cast_f2b<<<N * DD / 1024, tb, 0, stream>>>(x, xb);
    cast5_f2b<<<dim3(1024, 5), tb, 0, stream>>>(Wq, Wk, Wv, Wo, k1w, Wqb);

    gemm_proj<0><<<gp, tb, 0, stream>>>(xb, Wqb, nullptr, Qb, nullptr, DD);
    gemm_proj<0><<<gp, tb, 0, stream>>>(xb, Wkb, nullptr, Kb, nullptr, DD);
    gemm_proj<0><<<dim3(N / BN, DD / BM), tb, 0, stream>>>(Wvb, xb, nullptr, Vt, nullptr, N);  // Vt = Wv @ x^T

    attn_s_mfma<<<dim3(3, N / 128), tb, 0, stream>>>(Qb, Kb, S);
    attn_softmax<<<N / 4, tb, 0, stream>>>(S, P);
    attn_pv_mfma<<<dim3(8, N / 128), tb, 0, stream>>>(P, Vt, Cb);

    gemm_proj<1><<<gp, tb, 0, stream>>>(Cb, Wob, T, nullptr, x, DD);       // T = C@Wo^T + x
    ln_rows<true><<<N, tb, 0, stream>>>(T, nullptr, Ybf, lng, lnb);         // Ybf = LN(T)
    gemm_proj<2><<<gp, tb, 0, stream>>>(Ybf, k1wb, H0, nullptr, k1b, DD);   // H0 = relu(.+b)
    ln_rows<false><<<N, tb, 0, stream>>>(H0, H, nullptr, lng, lnb);         // H = LN(H0)
    k2_head<<<N / 4, tb, 0, stream>>>(H, k2w, k2b, out);
}

// Round 4
// 553.361 us; speedup vs baseline: 16.1225x; 1.0062x over previous
//
#include <hip/hip_runtime.h>
#include <math.h>

#define DD 1024
#define SS 4096
#define AP 128
#define LN_EPS 1e-6f
#define BM 128
#define BN 128
#define BK 32
#define BAND 384

typedef __bf16 bf16;
typedef __attribute__((ext_vector_type(4))) __bf16 bf16x4;
typedef __attribute__((ext_vector_type(8))) __bf16 bf16x8;
typedef __attribute__((ext_vector_type(4))) float f32x4;

#define GLOAD_LDS16(g, l)                                                   \
    __builtin_amdgcn_global_load_lds(                                        \
        (const __attribute__((address_space(1))) void*)(g),                  \
        (__attribute__((address_space(3))) void*)(l), 16, 0, 0)

// ---------------- casts ----------------
__global__ __launch_bounds__(256) void cast_f2b(const float* __restrict__ s,
                                                bf16* __restrict__ d) {
    const int i = (blockIdx.x * 256 + threadIdx.x) * 4;
    const float4 a = *(const float4*)(s + i);
    bf16x4 o;
    o[0] = (__bf16)a.x; o[1] = (__bf16)a.y; o[2] = (__bf16)a.z; o[3] = (__bf16)a.w;
    *(bf16x4*)(d + i) = o;
}

__global__ __launch_bounds__(256) void cast5_f2b(const float* __restrict__ w0,
                                                 const float* __restrict__ w1,
                                                 const float* __restrict__ w2,
                                                 const float* __restrict__ w3,
                                                 const float* __restrict__ w4,
                                                 bf16* __restrict__ d) {
    const float* s;
    switch (blockIdx.y) {
        case 0: s = w0; break;
        case 1: s = w1; break;
        case 2: s = w2; break;
        case 3: s = w3; break;
        default: s = w4; break;
    }
    const int i = (blockIdx.x * 256 + threadIdx.x) * 4;
    const float4 a = *(const float4*)(s + i);
    bf16x4 o;
    o[0] = (__bf16)a.x; o[1] = (__bf16)a.y; o[2] = (__bf16)a.z; o[3] = (__bf16)a.w;
    *(bf16x4*)(d + ((size_t)blockIdx.y << 20) + i) = o;
}

// ---------------- fused Q+K projection: one A pass, two B tiles ----------------
// grid (128, 8): x = m tile (XCD locality on A strip), y = n tile
__global__ __launch_bounds__(256) void gemm_qk(const bf16* __restrict__ A,
                                               const bf16* __restrict__ Wq,
                                               const bf16* __restrict__ Wk,
                                               bf16* __restrict__ Qo,
                                               bf16* __restrict__ Ko) {
    __shared__ bf16 As[BM * BK];
    __shared__ bf16 Bq[BN * BK];
    __shared__ bf16 Bk[BN * BK];
    const int tid = threadIdx.x;
    const int lane = tid & 63;
    const int wave = tid >> 6;
    const int wm = wave & 1;
    const int wn = wave >> 1;
    const int m0 = blockIdx.x * BM;
    const int n0 = blockIdx.y * BN;

    const int c = wave * 64 + lane;
    const int ar = c >> 2;
    const int ac = (c & 3) << 3;
    char* AsB = (char*)As;
    char* BqB = (char*)Bq;
    char* BkB = (char*)Bk;
    const int lr = lane & 15;
    const int lk = (lane >> 4) << 3;

    f32x4 accq[4][4] = {};
    f32x4 acck[4][4] = {};

    for (int kt = 0; kt < DD; kt += BK) {
        const bf16* ga0 = A + (size_t)(m0 + ar) * DD + kt + ac;
        const bf16* gq0 = Wq + (size_t)(n0 + ar) * DD + kt + ac;
        const bf16* gk0 = Wk + (size_t)(n0 + ar) * DD + kt + ac;
        GLOAD_LDS16(ga0, AsB + wave * 1024);
        GLOAD_LDS16(ga0 + (size_t)64 * DD, AsB + 4096 + wave * 1024);
        GLOAD_LDS16(gq0, BqB + wave * 1024);
        GLOAD_LDS16(gq0 + (size_t)64 * DD, BqB + 4096 + wave * 1024);
        GLOAD_LDS16(gk0, BkB + wave * 1024);
        GLOAD_LDS16(gk0 + (size_t)64 * DD, BkB + 4096 + wave * 1024);
        __syncthreads();

        bf16x8 af[4], bq[4], bk[4];
#pragma unroll
        for (int i = 0; i < 4; i++)
            af[i] = *(const bf16x8*)&As[(wm * 64 + i * 16 + lr) * BK + lk];
#pragma unroll
        for (int j = 0; j < 4; j++) {
            bq[j] = *(const bf16x8*)&Bq[(wn * 64 + j * 16 + lr) * BK + lk];
            bk[j] = *(const bf16x8*)&Bk[(wn * 64 + j * 16 + lr) * BK + lk];
        }
#pragma unroll
        for (int i = 0; i < 4; i++)
#pragma unroll
            for (int j = 0; j < 4; j++) {
                accq[i][j] = __builtin_amdgcn_mfma_f32_16x16x32_bf16(af[i], bq[j], accq[i][j], 0, 0, 0);
                acck[i][j] = __builtin_amdgcn_mfma_f32_16x16x32_bf16(af[i], bk[j], acck[i][j], 0, 0, 0);
            }
        __syncthreads();
    }

#pragma unroll
    for (int i = 0; i < 4; i++) {
        const int row = m0 + wm * 64 + i * 16 + ((lane >> 4) << 2);
#pragma unroll
        for (int j = 0; j < 4; j++) {
            const int col = n0 + wn * 64 + j * 16 + (lane & 15);
#pragma unroll
            for (int rr = 0; rr < 4; rr++) {
                const size_t idx = (size_t)(row + rr) * DD + col;
                Qo[idx] = (__bf16)accq[i][j][rr];
                Ko[idx] = (__bf16)acck[i][j][rr];
            }
        }
    }
}

// ---------------- bf16 MFMA GEMM: out[m,n] = sum_k A[m,k]*W[n,k] ----------------
// MODE 0: bf16 out; MODE 1: bf16(out + aux[m,n]); MODE 2: bf16 relu(out + aux[n])
// mx=1: blockIdx.x indexes m (XCD locality on A); mx=0: blockIdx.x indexes n
template<int MODE>
__global__ __launch_bounds__(256) void gemm_proj(const bf16* __restrict__ A,
                                                 const bf16* __restrict__ W,
                                                 bf16* __restrict__ outb,
                                                 const float* __restrict__ aux,
                                                 int ldo, int mx) {
    __shared__ bf16 As[BM * BK];
    __shared__ bf16 Bs[BN * BK];
    const int tid = threadIdx.x;
    const int lane = tid & 63;
    const int wave = tid >> 6;
    const int wm = wave & 1;
    const int wn = wave >> 1;
    const int m0 = (mx ? blockIdx.x : blockIdx.y) * BM;
    const int n0 = (mx ? blockIdx.y : blockIdx.x) * BN;

    const int c = wave * 64 + lane;
    const int ar = c >> 2;
    const int ac = (c & 3) << 3;
    char* AsB = (char*)As;
    char* BsB = (char*)Bs;
    const int lr = lane & 15;
    const int lk = (lane >> 4) << 3;

    f32x4 acc[4][4] = {};

    for (int kt = 0; kt < DD; kt += BK) {
        const bf16* ga0 = A + (size_t)(m0 + ar) * DD + kt + ac;
        const bf16* gb0 = W + (size_t)(n0 + ar) * DD + kt + ac;
        GLOAD_LDS16(ga0, AsB + wave * 1024);
        GLOAD_LDS16(ga0 + (size_t)64 * DD, AsB + 4096 + wave * 1024);
        GLOAD_LDS16(gb0, BsB + wave * 1024);
        GLOAD_LDS16(gb0 + (size_t)64 * DD, BsB + 4096 + wave * 1024);
        __syncthreads();

        bf16x8 af[4], bfr[4];
#pragma unroll
        for (int i = 0; i < 4; i++)
            af[i] = *(const bf16x8*)&As[(wm * 64 + i * 16 + lr) * BK + lk];
#pragma unroll
        for (int j = 0; j < 4; j++)
            bfr[j] = *(const bf16x8*)&Bs[(wn * 64 + j * 16 + lr) * BK + lk];
#pragma unroll
        for (int i = 0; i < 4; i++)
#pragma unroll
            for (int j = 0; j < 4; j++)
                acc[i][j] = __builtin_amdgcn_mfma_f32_16x16x32_bf16(af[i], bfr[j], acc[i][j], 0, 0, 0);
        __syncthreads();
    }

#pragma unroll
    for (int i = 0; i < 4; i++) {
        const int row = m0 + wm * 64 + i * 16 + ((lane >> 4) << 2);
#pragma unroll
        for (int j = 0; j < 4; j++) {
            const int col = n0 + wn * 64 + j * 16 + (lane & 15);
#pragma unroll
            for (int rr = 0; rr < 4; rr++) {
                const size_t idx = (size_t)(row + rr) * ldo + col;
                const float v = acc[i][j][rr];
                if (MODE == 0) outb[idx] = (__bf16)v;
                if (MODE == 1) outb[idx] = (__bf16)(v + aux[idx]);
                if (MODE == 2) outb[idx] = (__bf16)fmaxf(v + aux[col], 0.f);
            }
        }
    }
}

// ---------------- attention pass A1: raw banded scores S = Q @ K_band^T ----------------
__global__ __launch_bounds__(256) void attn_s_mfma(const bf16* __restrict__ Q,
                                                   const bf16* __restrict__ K,
                                                   float* __restrict__ S) {
    __shared__ bf16 As[BM * BK];
    __shared__ bf16 Bs[BN * BK];
    const int tid = threadIdx.x;
    const int lane = tid & 63;
    const int wave = tid >> 6;
    const int wm = wave & 1;
    const int wn = wave >> 1;
    const int t = blockIdx.y;
    const int m0 = t * 128;
    const long w0 = (long)t * 128 - 128 + (long)blockIdx.x * 128;

    const int c = wave * 64 + lane;
    const int ar = c >> 2;
    const int ac = (c & 3) << 3;
    char* AsB = (char*)As;
    char* BsB = (char*)Bs;
    const int lr = lane & 15;
    const int lk = (lane >> 4) << 3;

    f32x4 acc[4][4] = {};

    for (int kt = 0; kt < DD; kt += BK) {
        const bf16* ga0 = Q + (size_t)(m0 + ar) * DD + kt + ac;
        const bf16* gb0 = K + (w0 + ar) * DD + kt + ac;
        GLOAD_LDS16(ga0, AsB + wave * 1024);
        GLOAD_LDS16(ga0 + (size_t)64 * DD, AsB + 4096 + wave * 1024);
        GLOAD_LDS16(gb0, BsB + wave * 1024);
        GLOAD_LDS16(gb0 + (size_t)64 * DD, BsB + 4096 + wave * 1024);
        __syncthreads();

        bf16x8 af[4], bfr[4];
#pragma unroll
        for (int i = 0; i < 4; i++)
            af[i] = *(const bf16x8*)&As[(wm * 64 + i * 16 + lr) * BK + lk];
#pragma unroll
        for (int j = 0; j < 4; j++)
            bfr[j] = *(const bf16x8*)&Bs[(wn * 64 + j * 16 + lr) * BK + lk];
#pragma unroll
        for (int i = 0; i < 4; i++)
#pragma unroll
            for (int j = 0; j < 4; j++)
                acc[i][j] = __builtin_amdgcn_mfma_f32_16x16x32_bf16(af[i], bfr[j], acc[i][j], 0, 0, 0);
        __syncthreads();
    }

#pragma unroll
    for (int i = 0; i < 4; i++) {
        const int row = m0 + wm * 64 + i * 16 + ((lane >> 4) << 2);
#pragma unroll
        for (int j = 0; j < 4; j++) {
            const int col = blockIdx.x * 128 + wn * 64 + j * 16 + (lane & 15);
#pragma unroll
            for (int rr = 0; rr < 4; rr++)
                S[(size_t)(row + rr) * BAND + col] = acc[i][j][rr];
        }
    }
}

// ---------------- attention pass A2: masked softmax, normalized bf16 P ----------------
__global__ __launch_bounds__(256) void attn_softmax(const float* __restrict__ S,
                                                    bf16* __restrict__ P) {
    const int wave = threadIdx.x >> 6;
    const int lane = threadIdx.x & 63;
    const int g = blockIdx.x * 4 + wave;
    const int i = g & (SS - 1);
    const int j_start = ((i >> 7) << 7) - 128;
    const float scale = 0.03125f;
    float s[6];
    float m = -INFINITY;
#pragma unroll
    for (int t = 0; t < 6; t++) {
        const int jj = lane + t * 64;
        const int j = j_start + jj;
        const int dj = j - i;
        const bool valid = (j >= 0) && (j < SS) && (dj != 0) && (dj <= AP) && (dj >= -AP);
        const float v = S[(size_t)g * BAND + jj] * scale;
        s[t] = valid ? v : -INFINITY;
        m = fmaxf(m, s[t]);
    }
#pragma unroll
    for (int off = 32; off > 0; off >>= 1) m = fmaxf(m, __shfl_xor(m, off));
    float l = 0.f;
#pragma unroll
    for (int t = 0; t < 6; t++) {
        s[t] = __expf(s[t] - m);
        l += s[t];
    }
#pragma unroll
    for (int off = 32; off > 0; off >>= 1) l += __shfl_xor(l, off);
    const float inv = 1.f / l;
#pragma unroll
    for (int t = 0; t < 6; t++)
        P[(size_t)g * BAND + lane + t * 64] = (__bf16)(s[t] * inv);
}

// ---------------- attention pass B: C = P @ V_band ----------------
__global__ __launch_bounds__(256) void attn_pv_mfma(const bf16* __restrict__ P,
                                                    const bf16* __restrict__ Vt,
                                                    bf16* __restrict__ C) {
    __shared__ bf16 As[BM * BK];
    __shared__ bf16 Bs[BN * BK];
    const int tid = threadIdx.x;
    const int lane = tid & 63;
    const int wave = tid >> 6;
    const int wm = wave & 1;
    const int wn = wave >> 1;
    const int t = blockIdx.y;
    const int m0 = t * 128;
    const int n0 = blockIdx.x * 128;
    const bf16* Wb = Vt + (long)t * 128 - 128;

    const int c = wave * 64 + lane;
    const int ar = c >> 2;
    const int ac = (c & 3) << 3;
    char* AsB = (char*)As;
    char* BsB = (char*)Bs;
    const int lr = lane & 15;
    const int lk = (lane >> 4) << 3;

    f32x4 acc[4][4] = {};

    for (int kt = 0; kt < BAND; kt += BK) {
        const bf16* ga0 = P + (size_t)(m0 + ar) * BAND + kt + ac;
        const bf16* gb0 = Wb + (size_t)(n0 + ar) * (4 * SS) + kt + ac;
        GLOAD_LDS16(ga0, AsB + wave * 1024);
        GLOAD_LDS16(ga0 + (size_t)64 * BAND, AsB + 4096 + wave * 1024);
        GLOAD_LDS16(gb0, BsB + wave * 1024);
        GLOAD_LDS16(gb0 + (size_t)64 * (4 * SS), BsB + 4096 + wave * 1024);
        __syncthreads();

        bf16x8 af[4], bfr[4];
#pragma unroll
        for (int i = 0; i < 4; i++)
            af[i] = *(const bf16x8*)&As[(wm * 64 + i * 16 + lr) * BK + lk];
#pragma unroll
        for (int j = 0; j < 4; j++)
            bfr[j] = *(const bf16x8*)&Bs[(wn * 64 + j * 16 + lr) * BK + lk];
#pragma unroll
        for (int i = 0; i < 4; i++)
#pragma unroll
            for (int j = 0; j < 4; j++)
                acc[i][j] = __builtin_amdgcn_mfma_f32_16x16x32_bf16(af[i], bfr[j], acc[i][j], 0, 0, 0);
        __syncthreads();
    }

#pragma unroll
    for (int i = 0; i < 4; i++) {
        const int row = m0 + wm * 64 + i * 16 + ((lane >> 4) << 2);
#pragma unroll
        for (int j = 0; j < 4; j++) {
            const int col = n0 + wn * 64 + j * 16 + (lane & 15);
#pragma unroll
            for (int rr = 0; rr < 4; rr++)
                C[(size_t)(row + rr) * DD + col] = (__bf16)acc[i][j][rr];
        }
    }
}

// ---------------- layernorm rows of 1024, bf16 in / bf16 out ----------------
__global__ __launch_bounds__(256) void ln_rows_bb(const bf16* __restrict__ X,
                                                  bf16* __restrict__ Y,
                                                  const float* __restrict__ g,
                                                  const float* __restrict__ bta) {
    __shared__ float red[256], red2[256];
    const int r = blockIdx.x, tid = threadIdx.x;
    const bf16x4 xb4 = *(const bf16x4*)(X + (size_t)r * DD + tid * 4);
    float v0 = (float)xb4[0], v1 = (float)xb4[1], v2 = (float)xb4[2], v3 = (float)xb4[3];
    red[tid] = v0 + v1 + v2 + v3;
    red2[tid] = v0 * v0 + v1 * v1 + v2 * v2 + v3 * v3;
    __syncthreads();
    for (int s = 128; s > 0; s >>= 1) {
        if (tid < s) { red[tid] += red[tid + s]; red2[tid] += red2[tid + s]; }
        __syncthreads();
    }
    const float mu = red[0] * (1.f / DD);
    const float var = red2[0] * (1.f / DD) - mu * mu;
    const float rstd = rsqrtf(var + LN_EPS);
    const float4 g4 = *(const float4*)(g + tid * 4);
    const float4 b4 = *(const float4*)(bta + tid * 4);
    bf16x4 o;
    o[0] = (__bf16)((v0 - mu) * rstd * g4.x + b4.x);
    o[1] = (__bf16)((v1 - mu) * rstd * g4.y + b4.y);
    o[2] = (__bf16)((v2 - mu) * rstd * g4.z + b4.z);
    o[3] = (__bf16)((v3 - mu) * rstd * g4.w + b4.w);
    *(bf16x4*)(Y + (size_t)r * DD + tid * 4) = o;
}

// ---------------- fused LN2 + k2 head: out = sigmoid(LN(h0) . w2 + b2) ----------------
// z = rstd*(h0.u - mu*Sum(u)) + Sum(beta.w2) + b2, u = g*w2. 4 rows/block.
__global__ __launch_bounds__(256) void ln_k2_head(const bf16* __restrict__ H0,
                                                  const float* __restrict__ g,
                                                  const float* __restrict__ bta,
                                                  const float* __restrict__ w2,
                                                  const float* __restrict__ b2,
                                                  float* __restrict__ out) {
    __shared__ float ug[DD];
    __shared__ float red[256], red2[256];
    const int tid = threadIdx.x;
    const float4 g4 = *(const float4*)(g + tid * 4);
    const float4 w4 = *(const float4*)(w2 + tid * 4);
    const float4 b4 = *(const float4*)(bta + tid * 4);
    float4 u4;
    u4.x = g4.x * w4.x; u4.y = g4.y * w4.y; u4.z = g4.z * w4.z; u4.w = g4.w * w4.w;
    *(float4*)(ug + tid * 4) = u4;
    red[tid] = u4.x + u4.y + u4.z + u4.w;
    red2[tid] = b4.x * w4.x + b4.y * w4.y + b4.z * w4.z + b4.w * w4.w;
    __syncthreads();
    for (int s = 128; s > 0; s >>= 1) {
        if (tid < s) { red[tid] += red[tid + s]; red2[tid] += red2[tid + s]; }
        __syncthreads();
    }
    const float sum_u = red[0];
    const float sum_bw = red2[0];

    const int lane = tid & 63, wave = tid >> 6;
    const int r = blockIdx.x * 4 + wave;
    const bf16* h = H0 + (size_t)r * DD + lane * 16;
    const bf16x8 h0 = *(const bf16x8*)(h);
    const bf16x8 h1 = *(const bf16x8*)(h + 8);
    float s1 = 0.f, s2 = 0.f, s3 = 0.f;
#pragma unroll
    for (int e = 0; e < 8; e++) {
        const float a = (float)h0[e];
        const float b = (float)h1[e];
        const float ua = ug[lane * 16 + e];
        const float ub = ug[lane * 16 + 8 + e];
        s1 += a + b;
        s2 += a * a + b * b;
        s3 += a * ua + b * ub;
    }
#pragma unroll
    for (int off = 32; off > 0; off >>= 1) {
        s1 += __shfl_xor(s1, off);
        s2 += __shfl_xor(s2, off);
        s3 += __shfl_xor(s3, off);
    }
    if (lane == 0) {
        const float mu = s1 * (1.f / DD);
        const float var = s2 * (1.f / DD) - mu * mu;
        const float rstd = rsqrtf(var + LN_EPS);
        const float z = rstd * (s3 - mu * sum_u) + sum_bw + b2[0];
        out[r] = 1.f / (1.f + __expf(-z));
    }
}

extern "C" void kernel_launch(void* const* d_in, const int* in_sizes, int n_in,
                              void* d_out, int out_size, void* d_ws, size_t ws_size,
                              hipStream_t stream) {
    const float* x   = (const float*)d_in[0];
    const float* Wq  = (const float*)d_in[1];
    const float* Wk  = (const float*)d_in[2];
    const float* Wv  = (const float*)d_in[3];
    const float* Wo  = (const float*)d_in[4];
    const float* k1w = (const float*)d_in[5];
    const float* k1b = (const float*)d_in[6];
    const float* k2w = (const float*)d_in[7];
    const float* k2b = (const float*)d_in[8];
    const float* lng = (const float*)d_in[9];
    const float* lnb = (const float*)d_in[10];
    float* out = (float*)d_out;

    const int N = 4 * SS;  // 16384 rows
    char* ws = (char*)d_ws;
    // layout (MB). Kb and Vt are surrounded by valid buffers: banded passes
    // read up to 256 KB before/after them (masked / zero-weighted).
    bf16*  Qb  = (bf16*)(ws);                          //   0..32
    bf16*  Kb  = (bf16*)(ws + ((size_t)32  << 20));    //  32..64
    bf16*  Vt  = (bf16*)(ws + ((size_t)64  << 20));    //  64..96  [1024][16384]
    bf16*  xb  = (bf16*)(ws + ((size_t)96  << 20));    //  96..128 (dead after Vt gemm)
    float* S   = (float*)(ws + ((size_t)96  << 20));   //  96..120 (over dead xb)
    bf16*  P   = (bf16*)(ws + ((size_t)120 << 20));    // 120..132
    bf16*  Cb  = (bf16*)(ws + ((size_t)132 << 20));    // 132..164
    bf16*  T   = (bf16*)(ws + ((size_t)164 << 20));    // 164..196 (bf16 now)
    bf16*  Wqb = (bf16*)(ws + ((size_t)228 << 20));    // 228..238: 5 x 2MB weights
    bf16*  Wkb = Wqb + (1 << 20);
    bf16*  Wvb = Wkb + (1 << 20);
    bf16*  Wob = Wvb + (1 << 20);
    bf16*  k1wb = Wob + (1 << 20);
    // reuse: Ybf over Qb (dead after attn_s); H0 over Kb (dead after attn_s)
    bf16*  Ybf = Qb;
    bf16*  H0  = Kb;

    dim3 tb(256);

    cast_f2b<<<N * DD / 1024, tb, 0, stream>>>(x, xb);
    cast5_f2b<<<dim3(1024, 5), tb, 0, stream>>>(Wq, Wk, Wv, Wo, k1w, Wqb);

    // fused Q+K projection (grid x=m for XCD A-strip locality)
    gemm_qk<<<dim3(N / BM, DD / BN), tb, 0, stream>>>(xb, Wqb, Wkb, Qb, Kb);
    // Vt = Wv @ x^T ; big operand is xb (indexed by n=x) -> mx=0 keeps locality
    gemm_proj<0><<<dim3(N / BN, DD / BM), tb, 0, stream>>>(Wvb, xb, Vt, nullptr, N, 0);

    attn_s_mfma<<<dim3(3, N / 128), tb, 0, stream>>>(Qb, Kb, S);
    attn_softmax<<<N / 4, tb, 0, stream>>>(S, P);
    attn_pv_mfma<<<dim3(8, N / 128), tb, 0, stream>>>(P, Vt, Cb);

    gemm_proj<1><<<dim3(N / BM, DD / BN), tb, 0, stream>>>(Cb, Wob, T, x, DD, 1);    // T = C@Wo^T + x
    ln_rows_bb<<<N, tb, 0, stream>>>(T, Ybf, lng, lnb);                               // Ybf = LN(T)
    gemm_proj<2><<<dim3(N / BM, DD / BN), tb, 0, stream>>>(Ybf, k1wb, H0, k1b, DD, 1);// H0 = relu(.+b)
    ln_k2_head<<<N / 4, tb, 0, stream>>>(H0, lng, lnb, k2w, k2b, out);                // out = sigmoid(LN(H0).w2+b2)
}

// Round 5
// 409.402 us; speedup vs baseline: 21.7916x; 1.3516x over previous
//
#include <hip/hip_runtime.h>
#include <math.h>

#define DD 1024
#define SS 4096
#define AP 128
#define LN_EPS 1e-6f
#define BM 128
#define BN 128
#define BK 32
#define BAND 384

typedef __bf16 bf16;
typedef __attribute__((ext_vector_type(4))) __bf16 bf16x4;
typedef __attribute__((ext_vector_type(8))) __bf16 bf16x8;
typedef __attribute__((ext_vector_type(4))) float f32x4;

#define GLOAD_LDS16(g, l)                                                   \
    __builtin_amdgcn_global_load_lds(                                        \
        (const __attribute__((address_space(1))) void*)(g),                  \
        (__attribute__((address_space(3))) void*)(l), 16, 0, 0)

// ---------------- casts ----------------
__global__ __launch_bounds__(256) void cast_f2b(const float* __restrict__ s,
                                                bf16* __restrict__ d) {
    const int i = (blockIdx.x * 256 + threadIdx.x) * 4;
    const float4 a = *(const float4*)(s + i);
    bf16x4 o;
    o[0] = (__bf16)a.x; o[1] = (__bf16)a.y; o[2] = (__bf16)a.z; o[3] = (__bf16)a.w;
    *(bf16x4*)(d + i) = o;
}

// cast two plain weights (Wo, k1w) selected by blockIdx.y
__global__ __launch_bounds__(256) void cast2_f2b(const float* __restrict__ w0,
                                                 const float* __restrict__ w1,
                                                 bf16* __restrict__ d) {
    const float* s = blockIdx.y ? w1 : w0;
    const int i = (blockIdx.x * 256 + threadIdx.x) * 4;
    const float4 a = *(const float4*)(s + i);
    bf16x4 o;
    o[0] = (__bf16)a.x; o[1] = (__bf16)a.y; o[2] = (__bf16)a.z; o[3] = (__bf16)a.w;
    *(bf16x4*)(d + ((size_t)blockIdx.y << 20) + i) = o;
}

// cast + transpose three 1024x1024 weights (Wq, Wk, Wv) -> contiguous bf16 outputs
__global__ __launch_bounds__(256) void cast_t3(const float* __restrict__ w0,
                                               const float* __restrict__ w1,
                                               const float* __restrict__ w2,
                                               bf16* __restrict__ dbase) {
    __shared__ float tile[64][65];
    const float* in = (blockIdx.z == 0) ? w0 : (blockIdx.z == 1) ? w1 : w2;
    bf16* out = dbase + ((size_t)blockIdx.z << 20);
    const int r0 = blockIdx.y * 64, c0 = blockIdx.x * 64;
    const int lr = threadIdx.x >> 4;        // 0..15
    const int lc = (threadIdx.x & 15) * 4;  // 0..60
#pragma unroll
    for (int rr = 0; rr < 4; rr++) {
        const int row = lr + rr * 16;
        const float4 v = *(const float4*)(in + (size_t)(r0 + row) * DD + c0 + lc);
        tile[row][lc] = v.x; tile[row][lc + 1] = v.y;
        tile[row][lc + 2] = v.z; tile[row][lc + 3] = v.w;
    }
    __syncthreads();
#pragma unroll
    for (int rr = 0; rr < 4; rr++) {
        const int row = lr + rr * 16;
        bf16x4 o;
        o[0] = (__bf16)tile[lc + 0][row];
        o[1] = (__bf16)tile[lc + 1][row];
        o[2] = (__bf16)tile[lc + 2][row];
        o[3] = (__bf16)tile[lc + 3][row];
        *(bf16x4*)(out + (size_t)(c0 + row) * DD + r0 + lc) = o;
    }
}

// ---------------- bf16 MFMA GEMM: out[m,n] = sum_k A[m,k]*W[n,k] ----------------
// MODE 0: bf16 out; MODE 2: bf16 relu(out + aux[n])
// mx=1: blockIdx.x indexes m (XCD locality on A); mx=0: blockIdx.x indexes n
template<int MODE>
__global__ __launch_bounds__(256) void gemm_proj(const bf16* __restrict__ A,
                                                 const bf16* __restrict__ W,
                                                 bf16* __restrict__ outb,
                                                 const float* __restrict__ aux,
                                                 int ldo, int mx) {
    __shared__ bf16 As[BM * BK];
    __shared__ bf16 Bs[BN * BK];
    const int tid = threadIdx.x;
    const int lane = tid & 63;
    const int wave = tid >> 6;
    const int wm = wave & 1;
    const int wn = wave >> 1;
    const int m0 = (mx ? blockIdx.x : blockIdx.y) * BM;
    const int n0 = (mx ? blockIdx.y : blockIdx.x) * BN;

    const int c = wave * 64 + lane;
    const int ar = c >> 2;
    const int ac = (c & 3) << 3;
    char* AsB = (char*)As;
    char* BsB = (char*)Bs;
    const int lr = lane & 15;
    const int lk = (lane >> 4) << 3;

    f32x4 acc[4][4] = {};

    for (int kt = 0; kt < DD; kt += BK) {
        const bf16* ga0 = A + (size_t)(m0 + ar) * DD + kt + ac;
        const bf16* gb0 = W + (size_t)(n0 + ar) * DD + kt + ac;
        GLOAD_LDS16(ga0, AsB + wave * 1024);
        GLOAD_LDS16(ga0 + (size_t)64 * DD, AsB + 4096 + wave * 1024);
        GLOAD_LDS16(gb0, BsB + wave * 1024);
        GLOAD_LDS16(gb0 + (size_t)64 * DD, BsB + 4096 + wave * 1024);
        __syncthreads();

        bf16x8 af[4], bfr[4];
#pragma unroll
        for (int i = 0; i < 4; i++)
            af[i] = *(const bf16x8*)&As[(wm * 64 + i * 16 + lr) * BK + lk];
#pragma unroll
        for (int j = 0; j < 4; j++)
            bfr[j] = *(const bf16x8*)&Bs[(wn * 64 + j * 16 + lr) * BK + lk];
#pragma unroll
        for (int i = 0; i < 4; i++)
#pragma unroll
            for (int j = 0; j < 4; j++)
                acc[i][j] = __builtin_amdgcn_mfma_f32_16x16x32_bf16(af[i], bfr[j], acc[i][j], 0, 0, 0);
        __syncthreads();
    }

#pragma unroll
    for (int i = 0; i < 4; i++) {
        const int row = m0 + wm * 64 + i * 16 + ((lane >> 4) << 2);
#pragma unroll
        for (int j = 0; j < 4; j++) {
            const int col = n0 + wn * 64 + j * 16 + (lane & 15);
#pragma unroll
            for (int rr = 0; rr < 4; rr++) {
                const size_t idx = (size_t)(row + rr) * ldo + col;
                const float v = acc[i][j][rr];
                if (MODE == 0) outb[idx] = (__bf16)v;
                if (MODE == 2) outb[idx] = (__bf16)fmaxf(v + aux[col], 0.f);
            }
        }
    }
}

// ---------------- paired tiny 1024^3 GEMMs: z=0 -> Gt, z=1 -> W2 ----------------
__global__ __launch_bounds__(256) void gemm_pair(const bf16* __restrict__ A0,
                                                 const bf16* __restrict__ W0,
                                                 bf16* __restrict__ O0,
                                                 const bf16* __restrict__ A1,
                                                 const bf16* __restrict__ W1,
                                                 bf16* __restrict__ O1) {
    const bf16* A = blockIdx.z ? A1 : A0;
    const bf16* W = blockIdx.z ? W1 : W0;
    bf16* O = blockIdx.z ? O1 : O0;
    __shared__ bf16 As[BM * BK];
    __shared__ bf16 Bs[BN * BK];
    const int tid = threadIdx.x;
    const int lane = tid & 63;
    const int wave = tid >> 6;
    const int wm = wave & 1;
    const int wn = wave >> 1;
    const int m0 = blockIdx.y * BM;
    const int n0 = blockIdx.x * BN;

    const int c = wave * 64 + lane;
    const int ar = c >> 2;
    const int ac = (c & 3) << 3;
    char* AsB = (char*)As;
    char* BsB = (char*)Bs;
    const int lr = lane & 15;
    const int lk = (lane >> 4) << 3;

    f32x4 acc[4][4] = {};

    for (int kt = 0; kt < DD; kt += BK) {
        const bf16* ga0 = A + (size_t)(m0 + ar) * DD + kt + ac;
        const bf16* gb0 = W + (size_t)(n0 + ar) * DD + kt + ac;
        GLOAD_LDS16(ga0, AsB + wave * 1024);
        GLOAD_LDS16(ga0 + (size_t)64 * DD, AsB + 4096 + wave * 1024);
        GLOAD_LDS16(gb0, BsB + wave * 1024);
        GLOAD_LDS16(gb0 + (size_t)64 * DD, BsB + 4096 + wave * 1024);
        __syncthreads();

        bf16x8 af[4], bfr[4];
#pragma unroll
        for (int i = 0; i < 4; i++)
            af[i] = *(const bf16x8*)&As[(wm * 64 + i * 16 + lr) * BK + lk];
#pragma unroll
        for (int j = 0; j < 4; j++)
            bfr[j] = *(const bf16x8*)&Bs[(wn * 64 + j * 16 + lr) * BK + lk];
#pragma unroll
        for (int i = 0; i < 4; i++)
#pragma unroll
            for (int j = 0; j < 4; j++)
                acc[i][j] = __builtin_amdgcn_mfma_f32_16x16x32_bf16(af[i], bfr[j], acc[i][j], 0, 0, 0);
        __syncthreads();
    }

#pragma unroll
    for (int i = 0; i < 4; i++) {
        const int row = m0 + wm * 64 + i * 16 + ((lane >> 4) << 2);
#pragma unroll
        for (int j = 0; j < 4; j++) {
            const int col = n0 + wn * 64 + j * 16 + (lane & 15);
#pragma unroll
            for (int rr = 0; rr < 4; rr++)
                O[(size_t)(row + rr) * DD + col] = (__bf16)acc[i][j][rr];
        }
    }
}

// ---------------- attention pass A1: raw banded scores S = U @ x_band^T ----------------
__global__ __launch_bounds__(256) void attn_s_mfma(const bf16* __restrict__ U,
                                                   const bf16* __restrict__ X,
                                                   float* __restrict__ S) {
    __shared__ bf16 As[BM * BK];
    __shared__ bf16 Bs[BN * BK];
    const int tid = threadIdx.x;
    const int lane = tid & 63;
    const int wave = tid >> 6;
    const int wm = wave & 1;
    const int wn = wave >> 1;
    const int t = blockIdx.y;
    const int m0 = t * 128;
    const long w0 = (long)t * 128 - 128 + (long)blockIdx.x * 128;  // OOB -> bf16 guard buffers, masked in softmax

    const int c = wave * 64 + lane;
    const int ar = c >> 2;
    const int ac = (c & 3) << 3;
    char* AsB = (char*)As;
    char* BsB = (char*)Bs;
    const int lr = lane & 15;
    const int lk = (lane >> 4) << 3;

    f32x4 acc[4][4] = {};

    for (int kt = 0; kt < DD; kt += BK) {
        const bf16* ga0 = U + (size_t)(m0 + ar) * DD + kt + ac;
        const bf16* gb0 = X + (w0 + ar) * DD + kt + ac;
        GLOAD_LDS16(ga0, AsB + wave * 1024);
        GLOAD_LDS16(ga0 + (size_t)64 * DD, AsB + 4096 + wave * 1024);
        GLOAD_LDS16(gb0, BsB + wave * 1024);
        GLOAD_LDS16(gb0 + (size_t)64 * DD, BsB + 4096 + wave * 1024);
        __syncthreads();

        bf16x8 af[4], bfr[4];
#pragma unroll
        for (int i = 0; i < 4; i++)
            af[i] = *(const bf16x8*)&As[(wm * 64 + i * 16 + lr) * BK + lk];
#pragma unroll
        for (int j = 0; j < 4; j++)
            bfr[j] = *(const bf16x8*)&Bs[(wn * 64 + j * 16 + lr) * BK + lk];
#pragma unroll
        for (int i = 0; i < 4; i++)
#pragma unroll
            for (int j = 0; j < 4; j++)
                acc[i][j] = __builtin_amdgcn_mfma_f32_16x16x32_bf16(af[i], bfr[j], acc[i][j], 0, 0, 0);
        __syncthreads();
    }

#pragma unroll
    for (int i = 0; i < 4; i++) {
        const int row = m0 + wm * 64 + i * 16 + ((lane >> 4) << 2);
#pragma unroll
        for (int j = 0; j < 4; j++) {
            const int col = blockIdx.x * 128 + wn * 64 + j * 16 + (lane & 15);
#pragma unroll
            for (int rr = 0; rr < 4; rr++)
                S[(size_t)(row + rr) * BAND + col] = acc[i][j][rr];
        }
    }
}

// ---------------- attention pass A2: masked softmax, normalized bf16 P ----------------
__global__ __launch_bounds__(256) void attn_softmax(const float* __restrict__ S,
                                                    bf16* __restrict__ P) {
    const int wave = threadIdx.x >> 6;
    const int lane = threadIdx.x & 63;
    const int g = blockIdx.x * 4 + wave;
    const int i = g & (SS - 1);
    const int j_start = ((i >> 7) << 7) - 128;
    const float scale = 0.03125f;
    float s[6];
    float m = -INFINITY;
#pragma unroll
    for (int t = 0; t < 6; t++) {
        const int jj = lane + t * 64;
        const int j = j_start + jj;
        const int dj = j - i;
        const bool valid = (j >= 0) && (j < SS) && (dj != 0) && (dj <= AP) && (dj >= -AP);
        const float v = S[(size_t)g * BAND + jj] * scale;
        s[t] = valid ? v : -INFINITY;
        m = fmaxf(m, s[t]);
    }
#pragma unroll
    for (int off = 32; off > 0; off >>= 1) m = fmaxf(m, __shfl_xor(m, off));
    float l = 0.f;
#pragma unroll
    for (int t = 0; t < 6; t++) {
        s[t] = __expf(s[t] - m);
        l += s[t];
    }
#pragma unroll
    for (int off = 32; off > 0; off >>= 1) l += __shfl_xor(l, off);
    const float inv = 1.f / l;
#pragma unroll
    for (int t = 0; t < 6; t++)
        P[(size_t)g * BAND + lane + t * 64] = (__bf16)(s[t] * inv);
}

// ---------------- attention pass B + residual: T = P @ V2_band + x ----------------
__global__ __launch_bounds__(256) void attn_pv_mfma(const bf16* __restrict__ P,
                                                    const bf16* __restrict__ Vt,
                                                    const float* __restrict__ resid,
                                                    bf16* __restrict__ T) {
    __shared__ bf16 As[BM * BK];
    __shared__ bf16 Bs[BN * BK];
    const int tid = threadIdx.x;
    const int lane = tid & 63;
    const int wave = tid >> 6;
    const int wm = wave & 1;
    const int wn = wave >> 1;
    const int t = blockIdx.y;
    const int m0 = t * 128;
    const int n0 = blockIdx.x * 128;
    const bf16* Wb = Vt + (long)t * 128 - 128;

    const int c = wave * 64 + lane;
    const int ar = c >> 2;
    const int ac = (c & 3) << 3;
    char* AsB = (char*)As;
    char* BsB = (char*)Bs;
    const int lr = lane & 15;
    const int lk = (lane >> 4) << 3;

    f32x4 acc[4][4] = {};

    for (int kt = 0; kt < BAND; kt += BK) {
        const bf16* ga0 = P + (size_t)(m0 + ar) * BAND + kt + ac;
        const bf16* gb0 = Wb + (size_t)(n0 + ar) * (4 * SS) + kt + ac;
        GLOAD_LDS16(ga0, AsB + wave * 1024);
        GLOAD_LDS16(ga0 + (size_t)64 * BAND, AsB + 4096 + wave * 1024);
        GLOAD_LDS16(gb0, BsB + wave * 1024);
        GLOAD_LDS16(gb0 + (size_t)64 * (4 * SS), BsB + 4096 + wave * 1024);
        __syncthreads();

        bf16x8 af[4], bfr[4];
#pragma unroll
        for (int i = 0; i < 4; i++)
            af[i] = *(const bf16x8*)&As[(wm * 64 + i * 16 + lr) * BK + lk];
#pragma unroll
        for (int j = 0; j < 4; j++)
            bfr[j] = *(const bf16x8*)&Bs[(wn * 64 + j * 16 + lr) * BK + lk];
#pragma unroll
        for (int i = 0; i < 4; i++)
#pragma unroll
            for (int j = 0; j < 4; j++)
                acc[i][j] = __builtin_amdgcn_mfma_f32_16x16x32_bf16(af[i], bfr[j], acc[i][j], 0, 0, 0);
        __syncthreads();
    }

#pragma unroll
    for (int i = 0; i < 4; i++) {
        const int row = m0 + wm * 64 + i * 16 + ((lane >> 4) << 2);
#pragma unroll
        for (int j = 0; j < 4; j++) {
            const int col = n0 + wn * 64 + j * 16 + (lane & 15);
#pragma unroll
            for (int rr = 0; rr < 4; rr++) {
                const size_t idx = (size_t)(row + rr) * DD + col;
                T[idx] = (__bf16)(acc[i][j][rr] + resid[idx]);
            }
        }
    }
}

// ---------------- layernorm rows of 1024, bf16 in / bf16 out ----------------
__global__ __launch_bounds__(256) void ln_rows_bb(const bf16* __restrict__ X,
                                                  bf16* __restrict__ Y,
                                                  const float* __restrict__ g,
                                                  const float* __restrict__ bta) {
    __shared__ float red[256], red2[256];
    const int r = blockIdx.x, tid = threadIdx.x;
    const bf16x4 xb4 = *(const bf16x4*)(X + (size_t)r * DD + tid * 4);
    float v0 = (float)xb4[0], v1 = (float)xb4[1], v2 = (float)xb4[2], v3 = (float)xb4[3];
    red[tid] = v0 + v1 + v2 + v3;
    red2[tid] = v0 * v0 + v1 * v1 + v2 * v2 + v3 * v3;
    __syncthreads();
    for (int s = 128; s > 0; s >>= 1) {
        if (tid < s) { red[tid] += red[tid + s]; red2[tid] += red2[tid + s]; }
        __syncthreads();
    }
    const float mu = red[0] * (1.f / DD);
    const float var = red2[0] * (1.f / DD) - mu * mu;
    const float rstd = rsqrtf(var + LN_EPS);
    const float4 g4 = *(const float4*)(g + tid * 4);
    const float4 b4 = *(const float4*)(bta + tid * 4);
    bf16x4 o;
    o[0] = (__bf16)((v0 - mu) * rstd * g4.x + b4.x);
    o[1] = (__bf16)((v1 - mu) * rstd * g4.y + b4.y);
    o[2] = (__bf16)((v2 - mu) * rstd * g4.z + b4.z);
    o[3] = (__bf16)((v3 - mu) * rstd * g4.w + b4.w);
    *(bf16x4*)(Y + (size_t)r * DD + tid * 4) = o;
}

// ---------------- fused LN2 + k2 head ----------------
__global__ __launch_bounds__(256) void ln_k2_head(const bf16* __restrict__ H0,
                                                  const float* __restrict__ g,
                                                  const float* __restrict__ bta,
                                                  const float* __restrict__ w2,
                                                  const float* __restrict__ b2,
                                                  float* __restrict__ out) {
    __shared__ float ug[DD];
    __shared__ float red[256], red2[256];
    const int tid = threadIdx.x;
    const float4 g4 = *(const float4*)(g + tid * 4);
    const float4 w4 = *(const float4*)(w2 + tid * 4);
    const float4 b4 = *(const float4*)(bta + tid * 4);
    float4 u4;
    u4.x = g4.x * w4.x; u4.y = g4.y * w4.y; u4.z = g4.z * w4.z; u4.w = g4.w * w4.w;
    *(float4*)(ug + tid * 4) = u4;
    red[tid] = u4.x + u4.y + u4.z + u4.w;
    red2[tid] = b4.x * w4.x + b4.y * w4.y + b4.z * w4.z + b4.w * w4.w;
    __syncthreads();
    for (int s = 128; s > 0; s >>= 1) {
        if (tid < s) { red[tid] += red[tid + s]; red2[tid] += red2[tid + s]; }
        __syncthreads();
    }
    const float sum_u = red[0];
    const float sum_bw = red2[0];

    const int lane = tid & 63, wave = tid >> 6;
    const int r = blockIdx.x * 4 + wave;
    const bf16* h = H0 + (size_t)r * DD + lane * 16;
    const bf16x8 h0 = *(const bf16x8*)(h);
    const bf16x8 h1 = *(const bf16x8*)(h + 8);
    float s1 = 0.f, s2 = 0.f, s3 = 0.f;
#pragma unroll
    for (int e = 0; e < 8; e++) {
        const float a = (float)h0[e];
        const float b = (float)h1[e];
        const float ua = ug[lane * 16 + e];
        const float ub = ug[lane * 16 + 8 + e];
        s1 += a + b;
        s2 += a * a + b * b;
        s3 += a * ua + b * ub;
    }
#pragma unroll
    for (int off = 32; off > 0; off >>= 1) {
        s1 += __shfl_xor(s1, off);
        s2 += __shfl_xor(s2, off);
        s3 += __shfl_xor(s3, off);
    }
    if (lane == 0) {
        const float mu = s1 * (1.f / DD);
        const float var = s2 * (1.f / DD) - mu * mu;
        const float rstd = rsqrtf(var + LN_EPS);
        const float z = rstd * (s3 - mu * sum_u) + sum_bw + b2[0];
        out[r] = 1.f / (1.f + __expf(-z));
    }
}

extern "C" void kernel_launch(void* const* d_in, const int* in_sizes, int n_in,
                              void* d_out, int out_size, void* d_ws, size_t ws_size,
                              hipStream_t stream) {
    const float* x   = (const float*)d_in[0];
    const float* Wq  = (const float*)d_in[1];
    const float* Wk  = (const float*)d_in[2];
    const float* Wv  = (const float*)d_in[3];
    const float* Wo  = (const float*)d_in[4];
    const float* k1w = (const float*)d_in[5];
    const float* k1b = (const float*)d_in[6];
    const float* k2w = (const float*)d_in[7];
    const float* k2b = (const float*)d_in[8];
    const float* lng = (const float*)d_in[9];
    const float* lnb = (const float*)d_in[10];
    float* out = (float*)d_out;

    const int N = 4 * SS;  // 16384 rows
    char* ws = (char*)d_ws;
    // layout (MB). Banded passes read +/-256KB around xb and Vt2 -> those
    // neighbors must hold finite bf16 data (Ub / Vt2 / xb / P). Verified below.
    bf16*  Ub   = (bf16*)(ws);                          //   0..32  U = x@Gt^T
    bf16*  xb   = (bf16*)(ws + ((size_t)32  << 20));    //  32..64  guards: Ub | Vt2
    bf16*  Vt2  = (bf16*)(ws + ((size_t)64  << 20));    //  64..96  [1024][16384], guards: xb | P
    bf16*  P    = (bf16*)(ws + ((size_t)96  << 20));    //  96..108
    float* S    = (float*)(ws + ((size_t)108 << 20));   // 108..132
    bf16*  H0   = (bf16*)(ws + ((size_t)132 << 20));    // 132..164
    bf16*  T    = (bf16*)(ws + ((size_t)164 << 20));    // 164..196
    bf16*  Wqtb = (bf16*)(ws + ((size_t)196 << 20));    // 196..198 (transposed)
    bf16*  Wktb = Wqtb + (1 << 20);                     // 198..200 (transposed)
    bf16*  Wvtb = Wktb + (1 << 20);                     // 200..202 (transposed)
    bf16*  Wob  = Wvtb + (1 << 20);                     // 202..204
    bf16*  k1wb = Wob  + (1 << 20);                     // 204..206
    bf16*  Gtb  = k1wb + (1 << 20);                     // 206..208
    bf16*  W2b  = Gtb  + (1 << 20);                     // 208..210
    bf16*  Ybf  = Ub;  // reuse (Ub dead after attn_s)

    dim3 tb(256);

    cast_f2b<<<N * DD / 1024, tb, 0, stream>>>(x, xb);
    cast2_f2b<<<dim3(1024, 2), tb, 0, stream>>>(Wo, k1w, Wob);           // Wob, k1wb
    cast_t3<<<dim3(16, 16, 3), tb, 0, stream>>>(Wq, Wk, Wv, Wqtb);       // Wqtb, Wktb, Wvtb

    // Gt[n,k] = sum_d Wk[d,n]Wq[d,k]  |  W2[a,b] = sum_c Wo[a,c]Wv[c,b]
    gemm_pair<<<dim3(8, 8, 2), tb, 0, stream>>>(Wktb, Wqtb, Gtb, Wob, Wvtb, W2b);

    gemm_proj<0><<<dim3(N / BM, DD / BN), tb, 0, stream>>>(xb, Gtb, Ub, nullptr, DD, 1);   // U = x@Gt^T
    gemm_proj<0><<<dim3(N / BN, DD / BM), tb, 0, stream>>>(W2b, xb, Vt2, nullptr, N, 0);   // Vt2 = W2@x^T

    attn_s_mfma<<<dim3(3, N / 128), tb, 0, stream>>>(Ub, xb, S);
    attn_softmax<<<N / 4, tb, 0, stream>>>(S, P);
    attn_pv_mfma<<<dim3(8, N / 128), tb, 0, stream>>>(P, Vt2, x, T);     // T = P@V2 + x

    ln_rows_bb<<<N, tb, 0, stream>>>(T, Ybf, lng, lnb);                  // Ybf = LN(T)
    gemm_proj<2><<<dim3(N / BM, DD / BN), tb, 0, stream>>>(Ybf, k1wb, H0, k1b, DD, 1);  // H0 = relu(.+b)
    ln_k2_head<<<N / 4, tb, 0, stream>>>(H0, lng, lnb, k2w, k2b, out);
}

// Round 7
// 375.671 us; speedup vs baseline: 23.7483x; 1.0898x over previous
//
#include <hip/hip_runtime.h>
#include <math.h>

#define DD 1024
#define SS 4096
#define AP 128
#define LN_EPS 1e-6f
#define BK 32
#define BAND 384

typedef __bf16 bf16;
typedef __attribute__((ext_vector_type(4))) __bf16 bf16x4;
typedef __attribute__((ext_vector_type(8))) __bf16 bf16x8;
typedef __attribute__((ext_vector_type(4))) float f32x4;

#define GLOAD_LDS16(g, l)                                                   \
    __builtin_amdgcn_global_load_lds(                                        \
        (const __attribute__((address_space(1))) void*)(g),                  \
        (__attribute__((address_space(3))) void*)(l), 16, 0, 0)

// ---------------- x cast ----------------
__global__ __launch_bounds__(256) void cast_f2b(const float* __restrict__ s,
                                                bf16* __restrict__ d) {
    const int i = (blockIdx.x * 256 + threadIdx.x) * 4;
    const float4 a = *(const float4*)(s + i);
    bf16x4 o;
    o[0] = (__bf16)a.x; o[1] = (__bf16)a.y; o[2] = (__bf16)a.z; o[3] = (__bf16)a.w;
    *(bf16x4*)(d + i) = o;
}

// ---------------- weight prep: z=0 Wo cast, z=1 k1*g cast, z=2..4 transpose-cast Wq/Wk/Wv
__global__ __launch_bounds__(256) void prep_w(const float* __restrict__ Wo,
                                              const float* __restrict__ k1w,
                                              const float* __restrict__ lng,
                                              const float* __restrict__ Wq,
                                              const float* __restrict__ Wk,
                                              const float* __restrict__ Wv,
                                              bf16* __restrict__ Wob,
                                              bf16* __restrict__ k1g,
                                              bf16* __restrict__ Wtb) {
    const int z = blockIdx.y;
    if (z < 2) {
        const float* s = z ? k1w : Wo;
        bf16* d = z ? k1g : Wob;
        const int i = (blockIdx.x * 256 + threadIdx.x) * 4;
        float4 a = *(const float4*)(s + i);
        if (z) {
            const float4 g4 = *(const float4*)(lng + (i & (DD - 1)));
            a.x *= g4.x; a.y *= g4.y; a.z *= g4.z; a.w *= g4.w;
        }
        bf16x4 o;
        o[0] = (__bf16)a.x; o[1] = (__bf16)a.y; o[2] = (__bf16)a.z; o[3] = (__bf16)a.w;
        *(bf16x4*)(d + i) = o;
        return;
    }
    if (blockIdx.x >= 256) return;
    __shared__ float tile[64][65];
    const float* in = (z == 2) ? Wq : (z == 3) ? Wk : Wv;
    bf16* out = Wtb + ((size_t)(z - 2) << 20);
    const int r0 = (blockIdx.x >> 4) * 64, c0 = (blockIdx.x & 15) * 64;
    const int lr = threadIdx.x >> 4;
    const int lc = (threadIdx.x & 15) * 4;
#pragma unroll
    for (int rr = 0; rr < 4; rr++) {
        const int row = lr + rr * 16;
        const float4 v = *(const float4*)(in + (size_t)(r0 + row) * DD + c0 + lc);
        tile[row][lc] = v.x; tile[row][lc + 1] = v.y;
        tile[row][lc + 2] = v.z; tile[row][lc + 3] = v.w;
    }
    __syncthreads();
#pragma unroll
    for (int rr = 0; rr < 4; rr++) {
        const int row = lr + rr * 16;
        bf16x4 o;
        o[0] = (__bf16)tile[lc + 0][row];
        o[1] = (__bf16)tile[lc + 1][row];
        o[2] = (__bf16)tile[lc + 2][row];
        o[3] = (__bf16)tile[lc + 3][row];
        *(bf16x4*)(out + (size_t)(c0 + row) * DD + r0 + lc) = o;
    }
}

// ---------------- u1[n] = sum_k g[k]k1[n,k]; c1b[n] = sum_k beta[k]k1[n,k] + k1b[n]
__global__ __launch_bounds__(256) void prep_vec(const float* __restrict__ k1w,
                                                const float* __restrict__ lng,
                                                const float* __restrict__ lnb,
                                                const float* __restrict__ k1b,
                                                float* __restrict__ u1,
                                                float* __restrict__ c1b) {
    const int lane = threadIdx.x & 63, wave = threadIdx.x >> 6;
    const int n = blockIdx.x * 4 + wave;
    const float* row = k1w + (size_t)n * DD + lane * 16;
    float su = 0.f, sb = 0.f;
#pragma unroll
    for (int q = 0; q < 4; q++) {
        const float4 a = *(const float4*)(row + q * 4);
        const float4 g4 = *(const float4*)(lng + lane * 16 + q * 4);
        const float4 b4 = *(const float4*)(lnb + lane * 16 + q * 4);
        su += a.x * g4.x + a.y * g4.y + a.z * g4.z + a.w * g4.w;
        sb += a.x * b4.x + a.y * b4.y + a.z * b4.z + a.w * b4.w;
    }
#pragma unroll
    for (int off = 32; off > 0; off >>= 1) {
        su += __shfl_xor(su, off);
        sb += __shfl_xor(sb, off);
    }
    if (lane == 0) {
        u1[n] = su;
        c1b[n] = sb + k1b[n];
    }
}

// ---------------- paired tiny 1024^3 GEMMs: z=0 -> Gt, z=1 -> W2 (128x128 tiles) ----------------
__global__ __launch_bounds__(256) void gemm_pair(const bf16* __restrict__ A0,
                                                 const bf16* __restrict__ W0,
                                                 bf16* __restrict__ O0,
                                                 const bf16* __restrict__ A1,
                                                 const bf16* __restrict__ W1,
                                                 bf16* __restrict__ O1) {
    const bf16* A = blockIdx.z ? A1 : A0;
    const bf16* W = blockIdx.z ? W1 : W0;
    bf16* O = blockIdx.z ? O1 : O0;
    __shared__ bf16 As[128 * BK];
    __shared__ bf16 Bs[128 * BK];
    const int tid = threadIdx.x;
    const int lane = tid & 63;
    const int wave = tid >> 6;
    const int wm = wave & 1;
    const int wn = wave >> 1;
    const int m0 = blockIdx.y * 128;
    const int n0 = blockIdx.x * 128;

    const int c = wave * 64 + lane;
    const int ar = c >> 2;
    const int ac = (c & 3) << 3;
    char* AsB = (char*)As;
    char* BsB = (char*)Bs;
    const int lr = lane & 15;
    const int lk = (lane >> 4) << 3;

    f32x4 acc[4][4] = {};

    for (int kt = 0; kt < DD; kt += BK) {
        const bf16* ga0 = A + (size_t)(m0 + ar) * DD + kt + ac;
        const bf16* gb0 = W + (size_t)(n0 + ar) * DD + kt + ac;
        GLOAD_LDS16(ga0, AsB + wave * 1024);
        GLOAD_LDS16(ga0 + (size_t)64 * DD, AsB + 4096 + wave * 1024);
        GLOAD_LDS16(gb0, BsB + wave * 1024);
        GLOAD_LDS16(gb0 + (size_t)64 * DD, BsB + 4096 + wave * 1024);
        __syncthreads();

        bf16x8 af[4], bfr[4];
#pragma unroll
        for (int i = 0; i < 4; i++)
            af[i] = *(const bf16x8*)&As[(wm * 64 + i * 16 + lr) * BK + lk];
#pragma unroll
        for (int j = 0; j < 4; j++)
            bfr[j] = *(const bf16x8*)&Bs[(wn * 64 + j * 16 + lr) * BK + lk];
#pragma unroll
        for (int i = 0; i < 4; i++)
#pragma unroll
            for (int j = 0; j < 4; j++)
                acc[i][j] = __builtin_amdgcn_mfma_f32_16x16x32_bf16(af[i], bfr[j], acc[i][j], 0, 0, 0);
        __syncthreads();
    }

#pragma unroll
    for (int i = 0; i < 4; i++) {
        const int row = m0 + wm * 64 + i * 16 + ((lane >> 4) << 2);
#pragma unroll
        for (int j = 0; j < 4; j++) {
            const int col = n0 + wn * 64 + j * 16 + (lane & 15);
#pragma unroll
            for (int rr = 0; rr < 4; rr++)
                O[(size_t)(row + rr) * DD + col] = (__bf16)acc[i][j][rr];
        }
    }
}

// ---------------- merged U / Vt2 GEMM: 256x128 tiles, 512 threads, flat grid 1024 ----------------
// id<512:  U  = xb @ Gt^T   m0=(id&63)*256,  n0=(id>>6)*128, ldo=DD
// id>=512: Vt2 = W2 @ xb^T  m0=(id>>7)*256, n0=(id&127)*128, ldo=4*SS
__global__ __launch_bounds__(512) void gemm_uv(const bf16* __restrict__ xb,
                                               const bf16* __restrict__ Gt,
                                               const bf16* __restrict__ W2,
                                               bf16* __restrict__ Ub,
                                               bf16* __restrict__ Vt2) {
    __shared__ bf16 As[256 * BK];
    __shared__ bf16 Bs[128 * BK];
    int id = blockIdx.x;
    const bf16* A;
    const bf16* W;
    bf16* O;
    int m0, n0, ldo;
    if (id < 512) {
        A = xb; W = Gt; O = Ub;
        m0 = (id & 63) * 256; n0 = (id >> 6) * 128; ldo = DD;
    } else {
        id -= 512;
        A = W2; W = xb; O = Vt2;
        m0 = (id >> 7) * 256; n0 = (id & 127) * 128; ldo = 4 * SS;
    }
    const int tid = threadIdx.x;
    const int lane = tid & 63;
    const int wave = tid >> 6;     // 0..7
    const int wm = wave & 3;       // 4 m-strips of 64
    const int wn = wave >> 2;      // 2 n-strips of 64

    const int ar = tid >> 2;            // chunk row (0..127), A second half +128
    const int ac = (tid & 3) << 3;
    char* AsB = (char*)As;
    char* BsB = (char*)Bs;
    const int lr = lane & 15;
    const int lk = (lane >> 4) << 3;

    f32x4 acc[4][4] = {};

    for (int kt = 0; kt < DD; kt += BK) {
        const bf16* ga0 = A + (size_t)(m0 + ar) * DD + kt + ac;
        const bf16* gb0 = W + (size_t)(n0 + ar) * DD + kt + ac;
        GLOAD_LDS16(ga0, AsB + wave * 1024);
        GLOAD_LDS16(ga0 + (size_t)128 * DD, AsB + 8192 + wave * 1024);
        GLOAD_LDS16(gb0, BsB + wave * 1024);  // 512 chunks over 512 threads; wave stride = 64 lanes * 16B = 1024
        __syncthreads();

        bf16x8 af[4], bfr[4];
#pragma unroll
        for (int i = 0; i < 4; i++)
            af[i] = *(const bf16x8*)&As[(wm * 64 + i * 16 + lr) * BK + lk];
#pragma unroll
        for (int j = 0; j < 4; j++)
            bfr[j] = *(const bf16x8*)&Bs[(wn * 64 + j * 16 + lr) * BK + lk];
#pragma unroll
        for (int i = 0; i < 4; i++)
#pragma unroll
            for (int j = 0; j < 4; j++)
                acc[i][j] = __builtin_amdgcn_mfma_f32_16x16x32_bf16(af[i], bfr[j], acc[i][j], 0, 0, 0);
        __syncthreads();
    }

#pragma unroll
    for (int i = 0; i < 4; i++) {
        const int row = m0 + wm * 64 + i * 16 + ((lane >> 4) << 2);
#pragma unroll
        for (int j = 0; j < 4; j++) {
            const int col = n0 + wn * 64 + j * 16 + (lane & 15);
#pragma unroll
            for (int rr = 0; rr < 4; rr++)
                O[(size_t)(row + rr) * ldo + col] = (__bf16)acc[i][j][rr];
        }
    }
}

// ---------------- k1 GEMM with folded LN1: H0 = relu(rstd*(T@k1g^T) - rstd*mu*u1 + c1b)
// grid (64, 8): 256x128 tiles, 512 threads
__global__ __launch_bounds__(512) void gemm_k1(const bf16* __restrict__ T,
                                               const bf16* __restrict__ k1g,
                                               const float* __restrict__ mu,
                                               const float* __restrict__ rstd,
                                               const float* __restrict__ u1,
                                               const float* __restrict__ c1b,
                                               bf16* __restrict__ H0) {
    __shared__ bf16 As[256 * BK];
    __shared__ bf16 Bs[128 * BK];
    const int m0 = blockIdx.x * 256;
    const int n0 = blockIdx.y * 128;
    const int tid = threadIdx.x;
    const int lane = tid & 63;
    const int wave = tid >> 6;
    const int wm = wave & 3;
    const int wn = wave >> 2;

    const int ar = tid >> 2;
    const int ac = (tid & 3) << 3;
    char* AsB = (char*)As;
    char* BsB = (char*)Bs;
    const int lr = lane & 15;
    const int lk = (lane >> 4) << 3;

    f32x4 acc[4][4] = {};

    for (int kt = 0; kt < DD; kt += BK) {
        const bf16* ga0 = T + (size_t)(m0 + ar) * DD + kt + ac;
        const bf16* gb0 = k1g + (size_t)(n0 + ar) * DD + kt + ac;
        GLOAD_LDS16(ga0, AsB + wave * 1024);
        GLOAD_LDS16(ga0 + (size_t)128 * DD, AsB + 8192 + wave * 1024);
        GLOAD_LDS16(gb0, BsB + wave * 1024);  // wave stride 1024 (see gemm_uv)
        __syncthreads();

        bf16x8 af[4], bfr[4];
#pragma unroll
        for (int i = 0; i < 4; i++)
            af[i] = *(const bf16x8*)&As[(wm * 64 + i * 16 + lr) * BK + lk];
#pragma unroll
        for (int j = 0; j < 4; j++)
            bfr[j] = *(const bf16x8*)&Bs[(wn * 64 + j * 16 + lr) * BK + lk];
#pragma unroll
        for (int i = 0; i < 4; i++)
#pragma unroll
            for (int j = 0; j < 4; j++)
                acc[i][j] = __builtin_amdgcn_mfma_f32_16x16x32_bf16(af[i], bfr[j], acc[i][j], 0, 0, 0);
        __syncthreads();
    }

#pragma unroll
    for (int i = 0; i < 4; i++) {
        const int row = m0 + wm * 64 + i * 16 + ((lane >> 4) << 2);
#pragma unroll
        for (int j = 0; j < 4; j++) {
            const int col = n0 + wn * 64 + j * 16 + (lane & 15);
            const float u1c = u1[col];
            const float cbc = c1b[col];
#pragma unroll
            for (int rr = 0; rr < 4; rr++) {
                const int r = row + rr;
                const float v = rstd[r] * (acc[i][j][rr] - mu[r] * u1c) + cbc;
                H0[(size_t)r * DD + col] = (__bf16)fmaxf(v, 0.f);
            }
        }
    }
}

// ---------------- attention pass A1: raw banded scores S = U @ x_band^T ----------------
__global__ __launch_bounds__(256) void attn_s_mfma(const bf16* __restrict__ U,
                                                   const bf16* __restrict__ X,
                                                   float* __restrict__ S) {
    __shared__ bf16 As[128 * BK];
    __shared__ bf16 Bs[128 * BK];
    const int tid = threadIdx.x;
    const int lane = tid & 63;
    const int wave = tid >> 6;
    const int wm = wave & 1;
    const int wn = wave >> 1;
    const int t = blockIdx.y;
    const int m0 = t * 128;
    const long w0 = (long)t * 128 - 128 + (long)blockIdx.x * 128;  // OOB -> bf16 guard buffers, masked in softmax

    const int c = wave * 64 + lane;
    const int ar = c >> 2;
    const int ac = (c & 3) << 3;
    char* AsB = (char*)As;
    char* BsB = (char*)Bs;
    const int lr = lane & 15;
    const int lk = (lane >> 4) << 3;

    f32x4 acc[4][4] = {};

    for (int kt = 0; kt < DD; kt += BK) {
        const bf16* ga0 = U + (size_t)(m0 + ar) * DD + kt + ac;
        const bf16* gb0 = X + (w0 + ar) * DD + kt + ac;
        GLOAD_LDS16(ga0, AsB + wave * 1024);
        GLOAD_LDS16(ga0 + (size_t)64 * DD, AsB + 4096 + wave * 1024);
        GLOAD_LDS16(gb0, BsB + wave * 1024);
        GLOAD_LDS16(gb0 + (size_t)64 * DD, BsB + 4096 + wave * 1024);
        __syncthreads();

        bf16x8 af[4], bfr[4];
#pragma unroll
        for (int i = 0; i < 4; i++)
            af[i] = *(const bf16x8*)&As[(wm * 64 + i * 16 + lr) * BK + lk];
#pragma unroll
        for (int j = 0; j < 4; j++)
            bfr[j] = *(const bf16x8*)&Bs[(wn * 64 + j * 16 + lr) * BK + lk];
#pragma unroll
        for (int i = 0; i < 4; i++)
#pragma unroll
            for (int j = 0; j < 4; j++)
                acc[i][j] = __builtin_amdgcn_mfma_f32_16x16x32_bf16(af[i], bfr[j], acc[i][j], 0, 0, 0);
        __syncthreads();
    }

#pragma unroll
    for (int i = 0; i < 4; i++) {
        const int row = m0 + wm * 64 + i * 16 + ((lane >> 4) << 2);
#pragma unroll
        for (int j = 0; j < 4; j++) {
            const int col = blockIdx.x * 128 + wn * 64 + j * 16 + (lane & 15);
#pragma unroll
            for (int rr = 0; rr < 4; rr++)
                S[(size_t)(row + rr) * BAND + col] = acc[i][j][rr];
        }
    }
}

// ---------------- attention pass A2: masked softmax, normalized bf16 P ----------------
__global__ __launch_bounds__(256) void attn_softmax(const float* __restrict__ S,
                                                    bf16* __restrict__ P) {
    const int wave = threadIdx.x >> 6;
    const int lane = threadIdx.x & 63;
    const int g = blockIdx.x * 4 + wave;
    const int i = g & (SS - 1);
    const int j_start = ((i >> 7) << 7) - 128;
    const float scale = 0.03125f;
    float s[6];
    float m = -INFINITY;
#pragma unroll
    for (int t = 0; t < 6; t++) {
        const int jj = lane + t * 64;
        const int j = j_start + jj;
        const int dj = j - i;
        const bool valid = (j >= 0) && (j < SS) && (dj != 0) && (dj <= AP) && (dj >= -AP);
        const float v = S[(size_t)g * BAND + jj] * scale;
        s[t] = valid ? v : -INFINITY;
        m = fmaxf(m, s[t]);
    }
#pragma unroll
    for (int off = 32; off > 0; off >>= 1) m = fmaxf(m, __shfl_xor(m, off));
    float l = 0.f;
#pragma unroll
    for (int t = 0; t < 6; t++) {
        s[t] = __expf(s[t] - m);
        l += s[t];
    }
#pragma unroll
    for (int off = 32; off > 0; off >>= 1) l += __shfl_xor(l, off);
    const float inv = 1.f / l;
#pragma unroll
    for (int t = 0; t < 6; t++)
        P[(size_t)g * BAND + lane + t * 64] = (__bf16)(s[t] * inv);
}

// ---------------- attention pass B + residual: T = P @ V2_band + x ----------------
__global__ __launch_bounds__(256) void attn_pv_mfma(const bf16* __restrict__ P,
                                                    const bf16* __restrict__ Vt,
                                                    const float* __restrict__ resid,
                                                    bf16* __restrict__ T) {
    __shared__ bf16 As[128 * BK];
    __shared__ bf16 Bs[128 * BK];
    const int tid = threadIdx.x;
    const int lane = tid & 63;
    const int wave = tid >> 6;
    const int wm = wave & 1;
    const int wn = wave >> 1;
    const int t = blockIdx.y;
    const int m0 = t * 128;
    const int n0 = blockIdx.x * 128;
    const bf16* Wb = Vt + (long)t * 128 - 128;

    const int c = wave * 64 + lane;
    const int ar = c >> 2;
    const int ac = (c & 3) << 3;
    char* AsB = (char*)As;
    char* BsB = (char*)Bs;
    const int lr = lane & 15;
    const int lk = (lane >> 4) << 3;

    f32x4 acc[4][4] = {};

    for (int kt = 0; kt < BAND; kt += BK) {
        const bf16* ga0 = P + (size_t)(m0 + ar) * BAND + kt + ac;
        const bf16* gb0 = Wb + (size_t)(n0 + ar) * (4 * SS) + kt + ac;
        GLOAD_LDS16(ga0, AsB + wave * 1024);
        GLOAD_LDS16(ga0 + (size_t)64 * BAND, AsB + 4096 + wave * 1024);
        GLOAD_LDS16(gb0, BsB + wave * 1024);
        GLOAD_LDS16(gb0 + (size_t)64 * (4 * SS), BsB + 4096 + wave * 1024);
        __syncthreads();

        bf16x8 af[4], bfr[4];
#pragma unroll
        for (int i = 0; i < 4; i++)
            af[i] = *(const bf16x8*)&As[(wm * 64 + i * 16 + lr) * BK + lk];
#pragma unroll
        for (int j = 0; j < 4; j++)
            bfr[j] = *(const bf16x8*)&Bs[(wn * 64 + j * 16 + lr) * BK + lk];
#pragma unroll
        for (int i = 0; i < 4; i++)
#pragma unroll
            for (int j = 0; j < 4; j++)
                acc[i][j] = __builtin_amdgcn_mfma_f32_16x16x32_bf16(af[i], bfr[j], acc[i][j], 0, 0, 0);
        __syncthreads();
    }

#pragma unroll
    for (int i = 0; i < 4; i++) {
        const int row = m0 + wm * 64 + i * 16 + ((lane >> 4) << 2);
#pragma unroll
        for (int j = 0; j < 4; j++) {
            const int col = n0 + wn * 64 + j * 16 + (lane & 15);
#pragma unroll
            for (int rr = 0; rr < 4; rr++) {
                const size_t idx = (size_t)(row + rr) * DD + col;
                T[idx] = (__bf16)(acc[i][j][rr] + resid[idx]);
            }
        }
    }
}

// ---------------- per-row mean / rstd of T (wave per row) ----------------
__global__ __launch_bounds__(256) void row_stats(const bf16* __restrict__ T,
                                                 float* __restrict__ mu,
                                                 float* __restrict__ rstd) {
    const int lane = threadIdx.x & 63, wave = threadIdx.x >> 6;
    const int r = blockIdx.x * 4 + wave;
    const bf16* h = T + (size_t)r * DD + lane * 16;
    const bf16x8 h0 = *(const bf16x8*)(h);
    const bf16x8 h1 = *(const bf16x8*)(h + 8);
    float s1 = 0.f, s2 = 0.f;
#pragma unroll
    for (int e = 0; e < 8; e++) {
        const float a = (float)h0[e];
        const float b = (float)h1[e];
        s1 += a + b;
        s2 += a * a + b * b;
    }
#pragma unroll
    for (int off = 32; off > 0; off >>= 1) {
        s1 += __shfl_xor(s1, off);
        s2 += __shfl_xor(s2, off);
    }
    if (lane == 0) {
        const float m = s1 * (1.f / DD);
        const float var = s2 * (1.f / DD) - m * m;
        mu[r] = m;
        rstd[r] = rsqrtf(var + LN_EPS);
    }
}

// ---------------- fused LN2 + k2 head ----------------
__global__ __launch_bounds__(256) void ln_k2_head(const bf16* __restrict__ H0,
                                                  const float* __restrict__ g,
                                                  const float* __restrict__ bta,
                                                  const float* __restrict__ w2,
                                                  const float* __restrict__ b2,
                                                  float* __restrict__ out) {
    __shared__ float ug[DD];
    __shared__ float red[256], red2[256];
    const int tid = threadIdx.x;
    const float4 g4 = *(const float4*)(g + tid * 4);
    const float4 w4 = *(const float4*)(w2 + tid * 4);
    const float4 b4 = *(const float4*)(bta + tid * 4);
    float4 u4;
    u4.x = g4.x * w4.x; u4.y = g4.y * w4.y; u4.z = g4.z * w4.z; u4.w = g4.w * w4.w;
    *(float4*)(ug + tid * 4) = u4;
    red[tid] = u4.x + u4.y + u4.z + u4.w;
    red2[tid] = b4.x * w4.x + b4.y * w4.y + b4.z * w4.z + b4.w * w4.w;
    __syncthreads();
    for (int s = 128; s > 0; s >>= 1) {
        if (tid < s) { red[tid] += red[tid + s]; red2[tid] += red2[tid + s]; }
        __syncthreads();
    }
    const float sum_u = red[0];
    const float sum_bw = red2[0];

    const int lane = tid & 63, wave = tid >> 6;
    const int r = blockIdx.x * 4 + wave;
    const bf16* h = H0 + (size_t)r * DD + lane * 16;
    const bf16x8 h0 = *(const bf16x8*)(h);
    const bf16x8 h1 = *(const bf16x8*)(h + 8);
    float s1 = 0.f, s2 = 0.f, s3 = 0.f;
#pragma unroll
    for (int e = 0; e < 8; e++) {
        const float a = (float)h0[e];
        const float b = (float)h1[e];
        const float ua = ug[lane * 16 + e];
        const float ub = ug[lane * 16 + 8 + e];
        s1 += a + b;
        s2 += a * a + b * b;
        s3 += a * ua + b * ub;
    }
#pragma unroll
    for (int off = 32; off > 0; off >>= 1) {
        s1 += __shfl_xor(s1, off);
        s2 += __shfl_xor(s2, off);
        s3 += __shfl_xor(s3, off);
    }
    if (lane == 0) {
        const float m = s1 * (1.f / DD);
        const float var = s2 * (1.f / DD) - m * m;
        const float rs = rsqrtf(var + LN_EPS);
        const float z = rs * (s3 - m * sum_u) + sum_bw + b2[0];
        out[r] = 1.f / (1.f + __expf(-z));
    }
}

extern "C" void kernel_launch(void* const* d_in, const int* in_sizes, int n_in,
                              void* d_out, int out_size, void* d_ws, size_t ws_size,
                              hipStream_t stream) {
    const float* x   = (const float*)d_in[0];
    const float* Wq  = (const float*)d_in[1];
    const float* Wk  = (const float*)d_in[2];
    const float* Wv  = (const float*)d_in[3];
    const float* Wo  = (const float*)d_in[4];
    const float* k1w = (const float*)d_in[5];
    const float* k1b = (const float*)d_in[6];
    const float* k2w = (const float*)d_in[7];
    const float* k2b = (const float*)d_in[8];
    const float* lng = (const float*)d_in[9];
    const float* lnb = (const float*)d_in[10];
    float* out = (float*)d_out;

    const int N = 4 * SS;  // 16384 rows
    char* ws = (char*)d_ws;
    // layout (MB). Banded passes read +/-256KB around xb and Vt2 -> neighbors
    // must be valid bf16 (Ub | xb | Vt2 | P). Masked / zero-weighted.
    bf16*  Ub   = (bf16*)(ws);                          //   0..32  U = x@Gt^T
    bf16*  xb   = (bf16*)(ws + ((size_t)32  << 20));    //  32..64
    bf16*  Vt2  = (bf16*)(ws + ((size_t)64  << 20));    //  64..96  [1024][16384]
    bf16*  P    = (bf16*)(ws + ((size_t)96  << 20));    //  96..108
    float* S    = (float*)(ws + ((size_t)108 << 20));   // 108..132
    bf16*  H0   = (bf16*)(ws + ((size_t)132 << 20));    // 132..164
    bf16*  T    = (bf16*)(ws + ((size_t)164 << 20));    // 164..196
    bf16*  Wtb  = (bf16*)(ws + ((size_t)196 << 20));    // 196..202: Wq^T, Wk^T, Wv^T
    bf16*  Wqtb = Wtb;
    bf16*  Wktb = Wqtb + (1 << 20);
    bf16*  Wvtb = Wktb + (1 << 20);
    bf16*  Wob  = Wvtb + (1 << 20);                     // 202..204
    bf16*  k1g  = Wob  + (1 << 20);                     // 204..206
    bf16*  Gtb  = k1g  + (1 << 20);                     // 206..208
    bf16*  W2b  = Gtb  + (1 << 20);                     // 208..210
    float* muv  = (float*)(ws + ((size_t)210 << 20));   // 64 KB
    float* rsd  = muv + N;                              // 64 KB
    float* u1   = rsd + N;                              // 4 KB
    float* c1b  = u1 + DD;                              // 4 KB

    dim3 tb(256);

    cast_f2b<<<N * DD / 1024, tb, 0, stream>>>(x, xb);
    prep_w<<<dim3(1024, 5), tb, 0, stream>>>(Wo, k1w, lng, Wq, Wk, Wv, Wob, k1g, Wtb);
    prep_vec<<<DD / 4, tb, 0, stream>>>(k1w, lng, lnb, k1b, u1, c1b);

    // Gt = Wk^T @ Wq (bt-layout)  |  W2 = Wo @ Wv (bt on Wv^T)
    gemm_pair<<<dim3(8, 8, 2), tb, 0, stream>>>(Wktb, Wqtb, Gtb, Wob, Wvtb, W2b);

    gemm_uv<<<1024, dim3(512), 0, stream>>>(xb, Gtb, W2b, Ub, Vt2);

    attn_s_mfma<<<dim3(3, N / 128), tb, 0, stream>>>(Ub, xb, S);
    attn_softmax<<<N / 4, tb, 0, stream>>>(S, P);
    attn_pv_mfma<<<dim3(8, N / 128), tb, 0, stream>>>(P, Vt2, x, T);   // T = P@V2 + x

    row_stats<<<N / 4, tb, 0, stream>>>(T, muv, rsd);
    gemm_k1<<<dim3(64, 8), dim3(512), 0, stream>>>(T, k1g, muv, rsd, u1, c1b, H0);
    ln_k2_head<<<N / 4, tb, 0, stream>>>(H0, lng, lnb, k2w, k2b, out);
}

// Round 8
// 369.376 us; speedup vs baseline: 24.1530x; 1.0170x over previous
//
#include <hip/hip_runtime.h>
#include <math.h>

#define DD 1024
#define SS 4096
#define AP 128
#define LN_EPS 1e-6f
#define BK 32
#define BAND 384

typedef __bf16 bf16;
typedef __attribute__((ext_vector_type(4))) __bf16 bf16x4;
typedef __attribute__((ext_vector_type(8))) __bf16 bf16x8;
typedef __attribute__((ext_vector_type(4))) float f32x4;

#define GLOAD_LDS16(g, l)                                                   \
    __builtin_amdgcn_global_load_lds(                                        \
        (const __attribute__((address_space(1))) void*)(g),                  \
        (__attribute__((address_space(3))) void*)(l), 16, 0, 0)

// ---------------- merged prep: x cast | Wo cast | k1*g cast | 3 transposes | k1 row sums ----
// flat grid: [0,16384) x-cast; [16384,17408) Wo; [17408,18432) k1g;
// [18432,19200) transpose Wq/Wk/Wv (256 each); [19200,19456) prep_vec
__global__ __launch_bounds__(256) void prep_all(const float* __restrict__ x,
                                                const float* __restrict__ Wq,
                                                const float* __restrict__ Wk,
                                                const float* __restrict__ Wv,
                                                const float* __restrict__ Wo,
                                                const float* __restrict__ k1w,
                                                const float* __restrict__ k1b,
                                                const float* __restrict__ lng,
                                                const float* __restrict__ lnb,
                                                bf16* __restrict__ xb,
                                                bf16* __restrict__ Wob,
                                                bf16* __restrict__ k1g,
                                                bf16* __restrict__ Wtb,
                                                float* __restrict__ u1,
                                                float* __restrict__ c1b) {
    __shared__ float tile[64][65];
    const int bid = blockIdx.x;
    const int tid = threadIdx.x;
    if (bid < 16384) {  // x cast
        const int i = (bid * 256 + tid) * 4;
        const float4 a = *(const float4*)(x + i);
        bf16x4 o;
        o[0] = (__bf16)a.x; o[1] = (__bf16)a.y; o[2] = (__bf16)a.z; o[3] = (__bf16)a.w;
        *(bf16x4*)(xb + i) = o;
        return;
    }
    if (bid < 18432) {  // Wo cast / k1g = k1 * g cast
        const int b2 = bid - 16384;
        const int sel = b2 >> 10;
        const int bb = b2 & 1023;
        const float* s = sel ? k1w : Wo;
        bf16* d = sel ? k1g : Wob;
        const int i = (bb * 256 + tid) * 4;
        float4 a = *(const float4*)(s + i);
        if (sel) {
            const float4 g4 = *(const float4*)(lng + (i & (DD - 1)));
            a.x *= g4.x; a.y *= g4.y; a.z *= g4.z; a.w *= g4.w;
        }
        bf16x4 o;
        o[0] = (__bf16)a.x; o[1] = (__bf16)a.y; o[2] = (__bf16)a.z; o[3] = (__bf16)a.w;
        *(bf16x4*)(d + i) = o;
        return;
    }
    if (bid < 19200) {  // transpose-cast Wq/Wk/Wv
        const int t = bid - 18432;
        const int tz = t >> 8;
        const int tb_ = t & 255;
        const float* in = (tz == 0) ? Wq : (tz == 1) ? Wk : Wv;
        bf16* out = Wtb + ((size_t)tz << 20);
        const int r0 = (tb_ >> 4) * 64, c0 = (tb_ & 15) * 64;
        const int lr = tid >> 4;
        const int lc = (tid & 15) * 4;
#pragma unroll
        for (int rr = 0; rr < 4; rr++) {
            const int row = lr + rr * 16;
            const float4 v = *(const float4*)(in + (size_t)(r0 + row) * DD + c0 + lc);
            tile[row][lc] = v.x; tile[row][lc + 1] = v.y;
            tile[row][lc + 2] = v.z; tile[row][lc + 3] = v.w;
        }
        __syncthreads();
#pragma unroll
        for (int rr = 0; rr < 4; rr++) {
            const int row = lr + rr * 16;
            bf16x4 o;
            o[0] = (__bf16)tile[lc + 0][row];
            o[1] = (__bf16)tile[lc + 1][row];
            o[2] = (__bf16)tile[lc + 2][row];
            o[3] = (__bf16)tile[lc + 3][row];
            *(bf16x4*)(out + (size_t)(c0 + row) * DD + r0 + lc) = o;
        }
        return;
    }
    // prep_vec: u1[n] = sum_k g[k]k1[n,k]; c1b[n] = sum_k beta[k]k1[n,k] + k1b[n]
    const int pv = bid - 19200;
    const int lane = tid & 63, wave = tid >> 6;
    const int n = pv * 4 + wave;
    const float* row = k1w + (size_t)n * DD + lane * 16;
    float su = 0.f, sb = 0.f;
#pragma unroll
    for (int q = 0; q < 4; q++) {
        const float4 a = *(const float4*)(row + q * 4);
        const float4 g4 = *(const float4*)(lng + lane * 16 + q * 4);
        const float4 b4 = *(const float4*)(lnb + lane * 16 + q * 4);
        su += a.x * g4.x + a.y * g4.y + a.z * g4.z + a.w * g4.w;
        sb += a.x * b4.x + a.y * b4.y + a.z * b4.z + a.w * b4.w;
    }
#pragma unroll
    for (int off = 32; off > 0; off >>= 1) {
        su += __shfl_xor(su, off);
        sb += __shfl_xor(sb, off);
    }
    if (lane == 0) {
        u1[n] = su;
        c1b[n] = sb + k1b[n];
    }
}

// ---------------- paired tiny 1024^3 GEMMs: z=0 -> Gt, z=1 -> W2 ----------------
__global__ __launch_bounds__(256) void gemm_pair(const bf16* __restrict__ A0,
                                                 const bf16* __restrict__ W0,
                                                 bf16* __restrict__ O0,
                                                 const bf16* __restrict__ A1,
                                                 const bf16* __restrict__ W1,
                                                 bf16* __restrict__ O1) {
    const bf16* A = blockIdx.z ? A1 : A0;
    const bf16* W = blockIdx.z ? W1 : W0;
    bf16* O = blockIdx.z ? O1 : O0;
    __shared__ bf16 As[128 * BK];
    __shared__ bf16 Bs[128 * BK];
    const int tid = threadIdx.x;
    const int lane = tid & 63;
    const int wave = tid >> 6;
    const int wm = wave & 1;
    const int wn = wave >> 1;
    const int m0 = blockIdx.y * 128;
    const int n0 = blockIdx.x * 128;

    const int c = wave * 64 + lane;
    const int ar = c >> 2;
    const int ac = (c & 3) << 3;
    char* AsB = (char*)As;
    char* BsB = (char*)Bs;
    const int lr = lane & 15;
    const int lk = (lane >> 4) << 3;

    f32x4 acc[4][4] = {};

    for (int kt = 0; kt < DD; kt += BK) {
        const bf16* ga0 = A + (size_t)(m0 + ar) * DD + kt + ac;
        const bf16* gb0 = W + (size_t)(n0 + ar) * DD + kt + ac;
        GLOAD_LDS16(ga0, AsB + wave * 1024);
        GLOAD_LDS16(ga0 + (size_t)64 * DD, AsB + 4096 + wave * 1024);
        GLOAD_LDS16(gb0, BsB + wave * 1024);
        GLOAD_LDS16(gb0 + (size_t)64 * DD, BsB + 4096 + wave * 1024);
        __syncthreads();

        bf16x8 af[4], bfr[4];
#pragma unroll
        for (int i = 0; i < 4; i++)
            af[i] = *(const bf16x8*)&As[(wm * 64 + i * 16 + lr) * BK + lk];
#pragma unroll
        for (int j = 0; j < 4; j++)
            bfr[j] = *(const bf16x8*)&Bs[(wn * 64 + j * 16 + lr) * BK + lk];
#pragma unroll
        for (int i = 0; i < 4; i++)
#pragma unroll
            for (int j = 0; j < 4; j++)
                acc[i][j] = __builtin_amdgcn_mfma_f32_16x16x32_bf16(af[i], bfr[j], acc[i][j], 0, 0, 0);
        __syncthreads();
    }

#pragma unroll
    for (int i = 0; i < 4; i++) {
        const int row = m0 + wm * 64 + i * 16 + ((lane >> 4) << 2);
#pragma unroll
        for (int j = 0; j < 4; j++) {
            const int col = n0 + wn * 64 + j * 16 + (lane & 15);
#pragma unroll
            for (int rr = 0; rr < 4; rr++)
                O[(size_t)(row + rr) * DD + col] = (__bf16)acc[i][j][rr];
        }
    }
}

// ---------------- merged U / Vt2 GEMM: 256x128 tiles, 512 threads, flat grid 1024 ----------------
__global__ __launch_bounds__(512) void gemm_uv(const bf16* __restrict__ xb,
                                               const bf16* __restrict__ Gt,
                                               const bf16* __restrict__ W2,
                                               bf16* __restrict__ Ub,
                                               bf16* __restrict__ Vt2) {
    __shared__ bf16 As[256 * BK];
    __shared__ bf16 Bs[128 * BK];
    int id = blockIdx.x;
    const bf16* A;
    const bf16* W;
    bf16* O;
    int m0, n0, ldo;
    if (id < 512) {
        A = xb; W = Gt; O = Ub;
        m0 = (id & 63) * 256; n0 = (id >> 6) * 128; ldo = DD;
    } else {
        id -= 512;
        A = W2; W = xb; O = Vt2;
        m0 = (id >> 7) * 256; n0 = (id & 127) * 128; ldo = 4 * SS;
    }
    const int tid = threadIdx.x;
    const int lane = tid & 63;
    const int wave = tid >> 6;
    const int wm = wave & 3;
    const int wn = wave >> 2;

    const int ar = tid >> 2;
    const int ac = (tid & 3) << 3;
    char* AsB = (char*)As;
    char* BsB = (char*)Bs;
    const int lr = lane & 15;
    const int lk = (lane >> 4) << 3;

    f32x4 acc[4][4] = {};

    for (int kt = 0; kt < DD; kt += BK) {
        const bf16* ga0 = A + (size_t)(m0 + ar) * DD + kt + ac;
        const bf16* gb0 = W + (size_t)(n0 + ar) * DD + kt + ac;
        GLOAD_LDS16(ga0, AsB + wave * 1024);
        GLOAD_LDS16(ga0 + (size_t)128 * DD, AsB + 8192 + wave * 1024);
        GLOAD_LDS16(gb0, BsB + wave * 1024);
        __syncthreads();

        bf16x8 af[4], bfr[4];
#pragma unroll
        for (int i = 0; i < 4; i++)
            af[i] = *(const bf16x8*)&As[(wm * 64 + i * 16 + lr) * BK + lk];
#pragma unroll
        for (int j = 0; j < 4; j++)
            bfr[j] = *(const bf16x8*)&Bs[(wn * 64 + j * 16 + lr) * BK + lk];
#pragma unroll
        for (int i = 0; i < 4; i++)
#pragma unroll
            for (int j = 0; j < 4; j++)
                acc[i][j] = __builtin_amdgcn_mfma_f32_16x16x32_bf16(af[i], bfr[j], acc[i][j], 0, 0, 0);
        __syncthreads();
    }

#pragma unroll
    for (int i = 0; i < 4; i++) {
        const int row = m0 + wm * 64 + i * 16 + ((lane >> 4) << 2);
#pragma unroll
        for (int j = 0; j < 4; j++) {
            const int col = n0 + wn * 64 + j * 16 + (lane & 15);
#pragma unroll
            for (int rr = 0; rr < 4; rr++)
                O[(size_t)(row + rr) * ldo + col] = (__bf16)acc[i][j][rr];
        }
    }
}

// ---------------- k1 GEMM, folded LN1, partial-only output ----------------
// h = relu(rstd*(T@k1g^T) - rstd*mu*u1 + c1b); emits per-(row, 64-col strip)
// partials (sum h, sum h^2, sum h*g*w2) -> part_h[row][16][3]. No H0 store.
__global__ __launch_bounds__(512) void gemm_k1(const bf16* __restrict__ T,
                                               const bf16* __restrict__ k1g,
                                               const float* __restrict__ mu,
                                               const float* __restrict__ rstd,
                                               const float* __restrict__ u1,
                                               const float* __restrict__ c1b,
                                               const float* __restrict__ lng,
                                               const float* __restrict__ k2w,
                                               float* __restrict__ part_h) {
    __shared__ bf16 As[256 * BK];
    __shared__ bf16 Bs[128 * BK];
    const int m0 = blockIdx.x * 256;
    const int n0 = blockIdx.y * 128;
    const int tid = threadIdx.x;
    const int lane = tid & 63;
    const int wave = tid >> 6;
    const int wm = wave & 3;
    const int wn = wave >> 2;

    const int ar = tid >> 2;
    const int ac = (tid & 3) << 3;
    char* AsB = (char*)As;
    char* BsB = (char*)Bs;
    const int lr = lane & 15;
    const int lk = (lane >> 4) << 3;

    f32x4 acc[4][4] = {};

    for (int kt = 0; kt < DD; kt += BK) {
        const bf16* ga0 = T + (size_t)(m0 + ar) * DD + kt + ac;
        const bf16* gb0 = k1g + (size_t)(n0 + ar) * DD + kt + ac;
        GLOAD_LDS16(ga0, AsB + wave * 1024);
        GLOAD_LDS16(ga0 + (size_t)128 * DD, AsB + 8192 + wave * 1024);
        GLOAD_LDS16(gb0, BsB + wave * 1024);
        __syncthreads();

        bf16x8 af[4], bfr[4];
#pragma unroll
        for (int i = 0; i < 4; i++)
            af[i] = *(const bf16x8*)&As[(wm * 64 + i * 16 + lr) * BK + lk];
#pragma unroll
        for (int j = 0; j < 4; j++)
            bfr[j] = *(const bf16x8*)&Bs[(wn * 64 + j * 16 + lr) * BK + lk];
#pragma unroll
        for (int i = 0; i < 4; i++)
#pragma unroll
            for (int j = 0; j < 4; j++)
                acc[i][j] = __builtin_amdgcn_mfma_f32_16x16x32_bf16(af[i], bfr[j], acc[i][j], 0, 0, 0);
        __syncthreads();
    }

    float u1v[4], cbv[4], ugv[4];
#pragma unroll
    for (int j = 0; j < 4; j++) {
        const int col = n0 + wn * 64 + j * 16 + (lane & 15);
        u1v[j] = u1[col];
        cbv[j] = c1b[col];
        ugv[j] = lng[col] * k2w[col];
    }
    const int strip = blockIdx.y * 2 + wn;
#pragma unroll
    for (int i = 0; i < 4; i++) {
#pragma unroll
        for (int rr = 0; rr < 4; rr++) {
            const int row = m0 + wm * 64 + i * 16 + ((lane >> 4) << 2) + rr;
            const float mr = mu[row], rs = rstd[row];
            float s1 = 0.f, s2 = 0.f, s3 = 0.f;
#pragma unroll
            for (int j = 0; j < 4; j++) {
                const float v = rs * (acc[i][j][rr] - mr * u1v[j]) + cbv[j];
                const float h = fmaxf(v, 0.f);
                s1 += h; s2 += h * h; s3 += h * ugv[j];
            }
#pragma unroll
            for (int off = 8; off > 0; off >>= 1) {
                s1 += __shfl_xor(s1, off);
                s2 += __shfl_xor(s2, off);
                s3 += __shfl_xor(s3, off);
            }
            if ((lane & 15) == 0) {
                float* p = part_h + (size_t)row * 48 + strip * 3;
                p[0] = s1; p[1] = s2; p[2] = s3;
            }
        }
    }
}

// ---------------- attention pass A1: raw banded scores S = U @ x_band^T ----------------
__global__ __launch_bounds__(256) void attn_s_mfma(const bf16* __restrict__ U,
                                                   const bf16* __restrict__ X,
                                                   float* __restrict__ S) {
    __shared__ bf16 As[128 * BK];
    __shared__ bf16 Bs[128 * BK];
    const int tid = threadIdx.x;
    const int lane = tid & 63;
    const int wave = tid >> 6;
    const int wm = wave & 1;
    const int wn = wave >> 1;
    const int t = blockIdx.y;
    const int m0 = t * 128;
    const long w0 = (long)t * 128 - 128 + (long)blockIdx.x * 128;  // OOB -> bf16 guard buffers, masked in softmax

    const int c = wave * 64 + lane;
    const int ar = c >> 2;
    const int ac = (c & 3) << 3;
    char* AsB = (char*)As;
    char* BsB = (char*)Bs;
    const int lr = lane & 15;
    const int lk = (lane >> 4) << 3;

    f32x4 acc[4][4] = {};

    for (int kt = 0; kt < DD; kt += BK) {
        const bf16* ga0 = U + (size_t)(m0 + ar) * DD + kt + ac;
        const bf16* gb0 = X + (w0 + ar) * DD + kt + ac;
        GLOAD_LDS16(ga0, AsB + wave * 1024);
        GLOAD_LDS16(ga0 + (size_t)64 * DD, AsB + 4096 + wave * 1024);
        GLOAD_LDS16(gb0, BsB + wave * 1024);
        GLOAD_LDS16(gb0 + (size_t)64 * DD, BsB + 4096 + wave * 1024);
        __syncthreads();

        bf16x8 af[4], bfr[4];
#pragma unroll
        for (int i = 0; i < 4; i++)
            af[i] = *(const bf16x8*)&As[(wm * 64 + i * 16 + lr) * BK + lk];
#pragma unroll
        for (int j = 0; j < 4; j++)
            bfr[j] = *(const bf16x8*)&Bs[(wn * 64 + j * 16 + lr) * BK + lk];
#pragma unroll
        for (int i = 0; i < 4; i++)
#pragma unroll
            for (int j = 0; j < 4; j++)
                acc[i][j] = __builtin_amdgcn_mfma_f32_16x16x32_bf16(af[i], bfr[j], acc[i][j], 0, 0, 0);
        __syncthreads();
    }

#pragma unroll
    for (int i = 0; i < 4; i++) {
        const int row = m0 + wm * 64 + i * 16 + ((lane >> 4) << 2);
#pragma unroll
        for (int j = 0; j < 4; j++) {
            const int col = blockIdx.x * 128 + wn * 64 + j * 16 + (lane & 15);
#pragma unroll
            for (int rr = 0; rr < 4; rr++)
                S[(size_t)(row + rr) * BAND + col] = acc[i][j][rr];
        }
    }
}

// ---------------- attention pass A2: masked softmax, normalized bf16 P ----------------
__global__ __launch_bounds__(256) void attn_softmax(const float* __restrict__ S,
                                                    bf16* __restrict__ P) {
    const int wave = threadIdx.x >> 6;
    const int lane = threadIdx.x & 63;
    const int g = blockIdx.x * 4 + wave;
    const int i = g & (SS - 1);
    const int j_start = ((i >> 7) << 7) - 128;
    const float scale = 0.03125f;
    float s[6];
    float m = -INFINITY;
#pragma unroll
    for (int t = 0; t < 6; t++) {
        const int jj = lane + t * 64;
        const int j = j_start + jj;
        const int dj = j - i;
        const bool valid = (j >= 0) && (j < SS) && (dj != 0) && (dj <= AP) && (dj >= -AP);
        const float v = S[(size_t)g * BAND + jj] * scale;
        s[t] = valid ? v : -INFINITY;
        m = fmaxf(m, s[t]);
    }
#pragma unroll
    for (int off = 32; off > 0; off >>= 1) m = fmaxf(m, __shfl_xor(m, off));
    float l = 0.f;
#pragma unroll
    for (int t = 0; t < 6; t++) {
        s[t] = __expf(s[t] - m);
        l += s[t];
    }
#pragma unroll
    for (int off = 32; off > 0; off >>= 1) l += __shfl_xor(l, off);
    const float inv = 1.f / l;
#pragma unroll
    for (int t = 0; t < 6; t++)
        P[(size_t)g * BAND + lane + t * 64] = (__bf16)(s[t] * inv);
}

// ---------------- attention pass B + residual + T row-partials ----------------
// T = P @ V2_band + xb ; also emits per-(row, 64-col strip) (sum t, sum t^2)
__global__ __launch_bounds__(256) void attn_pv_mfma(const bf16* __restrict__ P,
                                                    const bf16* __restrict__ Vt,
                                                    const bf16* __restrict__ xres,
                                                    bf16* __restrict__ T,
                                                    float* __restrict__ part_t) {
    __shared__ bf16 As[128 * BK];
    __shared__ bf16 Bs[128 * BK];
    const int tid = threadIdx.x;
    const int lane = tid & 63;
    const int wave = tid >> 6;
    const int wm = wave & 1;
    const int wn = wave >> 1;
    const int t = blockIdx.y;
    const int m0 = t * 128;
    const int n0 = blockIdx.x * 128;
    const bf16* Wb = Vt + (long)t * 128 - 128;

    const int c = wave * 64 + lane;
    const int ar = c >> 2;
    const int ac = (c & 3) << 3;
    char* AsB = (char*)As;
    char* BsB = (char*)Bs;
    const int lr = lane & 15;
    const int lk = (lane >> 4) << 3;

    f32x4 acc[4][4] = {};

    for (int kt = 0; kt < BAND; kt += BK) {
        const bf16* ga0 = P + (size_t)(m0 + ar) * BAND + kt + ac;
        const bf16* gb0 = Wb + (size_t)(n0 + ar) * (4 * SS) + kt + ac;
        GLOAD_LDS16(ga0, AsB + wave * 1024);
        GLOAD_LDS16(ga0 + (size_t)64 * BAND, AsB + 4096 + wave * 1024);
        GLOAD_LDS16(gb0, BsB + wave * 1024);
        GLOAD_LDS16(gb0 + (size_t)64 * (4 * SS), BsB + 4096 + wave * 1024);
        __syncthreads();

        bf16x8 af[4], bfr[4];
#pragma unroll
        for (int i = 0; i < 4; i++)
            af[i] = *(const bf16x8*)&As[(wm * 64 + i * 16 + lr) * BK + lk];
#pragma unroll
        for (int j = 0; j < 4; j++)
            bfr[j] = *(const bf16x8*)&Bs[(wn * 64 + j * 16 + lr) * BK + lk];
#pragma unroll
        for (int i = 0; i < 4; i++)
#pragma unroll
            for (int j = 0; j < 4; j++)
                acc[i][j] = __builtin_amdgcn_mfma_f32_16x16x32_bf16(af[i], bfr[j], acc[i][j], 0, 0, 0);
        __syncthreads();
    }

    const int strip = blockIdx.x * 2 + wn;
#pragma unroll
    for (int i = 0; i < 4; i++) {
#pragma unroll
        for (int rr = 0; rr < 4; rr++) {
            const int row = m0 + wm * 64 + i * 16 + ((lane >> 4) << 2) + rr;
            float s1 = 0.f, s2 = 0.f;
#pragma unroll
            for (int j = 0; j < 4; j++) {
                const int col = n0 + wn * 64 + j * 16 + (lane & 15);
                const size_t idx = (size_t)row * DD + col;
                const __bf16 tv_b = (__bf16)(acc[i][j][rr] + (float)xres[idx]);
                T[idx] = tv_b;
                const float tv = (float)tv_b;
                s1 += tv; s2 += tv * tv;
            }
#pragma unroll
            for (int off = 8; off > 0; off >>= 1) {
                s1 += __shfl_xor(s1, off);
                s2 += __shfl_xor(s2, off);
            }
            if ((lane & 15) == 0) {
                float2 st; st.x = s1; st.y = s2;
                *(float2*)(part_t + (size_t)row * 32 + strip * 2) = st;
            }
        }
    }
}

// ---------------- reduce T partials -> per-row mu / rstd ----------------
__global__ __launch_bounds__(256) void row_stats_p(const float* __restrict__ part_t,
                                                   float* __restrict__ mu,
                                                   float* __restrict__ rstd) {
    const int r = blockIdx.x * 256 + threadIdx.x;
    const float* p = part_t + (size_t)r * 32;
    float s1 = 0.f, s2 = 0.f;
#pragma unroll
    for (int s = 0; s < 8; s++) {
        const float4 v = *(const float4*)(p + s * 4);
        s1 += v.x + v.z;
        s2 += v.y + v.w;
    }
    const float m = s1 * (1.f / DD);
    const float var = s2 * (1.f / DD) - m * m;
    mu[r] = m;
    rstd[r] = rsqrtf(var + LN_EPS);
}

// ---------------- reduce H partials -> sigmoid head ----------------
__global__ __launch_bounds__(256) void ln_k2_p(const float* __restrict__ part_h,
                                               const float* __restrict__ g,
                                               const float* __restrict__ bta,
                                               const float* __restrict__ w2,
                                               const float* __restrict__ b2,
                                               float* __restrict__ out) {
    __shared__ float red[256], red2[256];
    const int tid = threadIdx.x;
    const float4 g4 = *(const float4*)(g + tid * 4);
    const float4 w4 = *(const float4*)(w2 + tid * 4);
    const float4 b4 = *(const float4*)(bta + tid * 4);
    red[tid] = g4.x * w4.x + g4.y * w4.y + g4.z * w4.z + g4.w * w4.w;
    red2[tid] = b4.x * w4.x + b4.y * w4.y + b4.z * w4.z + b4.w * w4.w;
    __syncthreads();
    for (int s = 128; s > 0; s >>= 1) {
        if (tid < s) { red[tid] += red[tid + s]; red2[tid] += red2[tid + s]; }
        __syncthreads();
    }
    const float sum_u = red[0];
    const float sum_bw = red2[0];

    const int r = blockIdx.x * 256 + tid;
    const float* p = part_h + (size_t)r * 48;
    float s1 = 0.f, s2 = 0.f, s3 = 0.f;
#pragma unroll
    for (int s = 0; s < 16; s++) {
        s1 += p[s * 3 + 0];
        s2 += p[s * 3 + 1];
        s3 += p[s * 3 + 2];
    }
    const float m = s1 * (1.f / DD);
    const float var = s2 * (1.f / DD) - m * m;
    const float rs = rsqrtf(var + LN_EPS);
    const float z = rs * (s3 - m * sum_u) + sum_bw + b2[0];
    out[r] = 1.f / (1.f + __expf(-z));
}

extern "C" void kernel_launch(void* const* d_in, const int* in_sizes, int n_in,
                              void* d_out, int out_size, void* d_ws, size_t ws_size,
                              hipStream_t stream) {
    const float* x   = (const float*)d_in[0];
    const float* Wq  = (const float*)d_in[1];
    const float* Wk  = (const float*)d_in[2];
    const float* Wv  = (const float*)d_in[3];
    const float* Wo  = (const float*)d_in[4];
    const float* k1w = (const float*)d_in[5];
    const float* k1b = (const float*)d_in[6];
    const float* k2w = (const float*)d_in[7];
    const float* k2b = (const float*)d_in[8];
    const float* lng = (const float*)d_in[9];
    const float* lnb = (const float*)d_in[10];
    float* out = (float*)d_out;

    const int N = 4 * SS;  // 16384 rows
    char* ws = (char*)d_ws;
    // layout (MB). Banded passes read +/-256KB around xb and Vt2 -> neighbors
    // must be valid bf16 (Ub | xb | Vt2 | P). Masked / zero-weighted.
    bf16*  Ub   = (bf16*)(ws);                          //   0..32
    bf16*  xb   = (bf16*)(ws + ((size_t)32  << 20));    //  32..64
    bf16*  Vt2  = (bf16*)(ws + ((size_t)64  << 20));    //  64..96  [1024][16384]
    bf16*  P    = (bf16*)(ws + ((size_t)96  << 20));    //  96..108
    float* S    = (float*)(ws + ((size_t)108 << 20));   // 108..132
    bf16*  T    = (bf16*)(ws + ((size_t)164 << 20));    // 164..196
    bf16*  Wtb  = (bf16*)(ws + ((size_t)196 << 20));    // 196..202: Wq^T, Wk^T, Wv^T
    bf16*  Wqtb = Wtb;
    bf16*  Wktb = Wqtb + (1 << 20);
    bf16*  Wvtb = Wktb + (1 << 20);
    bf16*  Wob  = Wvtb + (1 << 20);                     // 202..204
    bf16*  k1g  = Wob  + (1 << 20);                     // 204..206
    bf16*  Gtb  = k1g  + (1 << 20);                     // 206..208
    bf16*  W2b  = Gtb  + (1 << 20);                     // 208..210
    float* muv    = (float*)(ws + ((size_t)210 << 20)); // 64 KB
    float* rsd    = muv + N;                            // 64 KB
    float* u1     = rsd + N;                            // 4 KB
    float* c1b    = u1 + DD;                            // 4 KB
    float* part_t = (float*)(ws + ((size_t)211 << 20)); // 211..213: [16384][16][2]
    float* part_h = (float*)(ws + ((size_t)214 << 20)); // 214..217: [16384][16][3]

    dim3 tb(256);

    prep_all<<<19456, tb, 0, stream>>>(x, Wq, Wk, Wv, Wo, k1w, k1b, lng, lnb,
                                       xb, Wob, k1g, Wtb, u1, c1b);

    // Gt = Wk^T @ Wq (bt-layout)  |  W2 = Wo @ Wv (bt on Wv^T)
    gemm_pair<<<dim3(8, 8, 2), tb, 0, stream>>>(Wktb, Wqtb, Gtb, Wob, Wvtb, W2b);

    gemm_uv<<<1024, dim3(512), 0, stream>>>(xb, Gtb, W2b, Ub, Vt2);

    attn_s_mfma<<<dim3(3, N / 128), tb, 0, stream>>>(Ub, xb, S);
    attn_softmax<<<N / 4, tb, 0, stream>>>(S, P);
    attn_pv_mfma<<<dim3(8, N / 128), tb, 0, stream>>>(P, Vt2, xb, T, part_t);

    row_stats_p<<<N / 256, tb, 0, stream>>>(part_t, muv, rsd);
    gemm_k1<<<dim3(64, 8), dim3(512), 0, stream>>>(T, k1g, muv, rsd, u1, c1b, lng, k2w, part_h);
    ln_k2_p<<<N / 256, tb, 0, stream>>>(part_h, lng, lnb, k2w, k2b, out);
}

// Round 9
// 340.554 us; speedup vs baseline: 26.1971x; 1.0846x over previous
//
#include <hip/hip_runtime.h>
#include <math.h>

#define DD 1024
#define SS 4096
#define AP 128
#define LN_EPS 1e-6f
#define BK 32
#define BAND 384

typedef __bf16 bf16;
typedef __attribute__((ext_vector_type(4))) __bf16 bf16x4;
typedef __attribute__((ext_vector_type(8))) __bf16 bf16x8;
typedef __attribute__((ext_vector_type(4))) float f32x4;

#define GLOAD_LDS16(g, l)                                                   \
    __builtin_amdgcn_global_load_lds(                                        \
        (const __attribute__((address_space(1))) void*)(g),                  \
        (__attribute__((address_space(3))) void*)(l), 16, 0, 0)

// ---------------- merged prep: x cast | Wo cast | k1*g cast | 3 transposes | k1 row sums ----
__global__ __launch_bounds__(256) void prep_all(const float* __restrict__ x,
                                                const float* __restrict__ Wq,
                                                const float* __restrict__ Wk,
                                                const float* __restrict__ Wv,
                                                const float* __restrict__ Wo,
                                                const float* __restrict__ k1w,
                                                const float* __restrict__ k1b,
                                                const float* __restrict__ lng,
                                                const float* __restrict__ lnb,
                                                bf16* __restrict__ xb,
                                                bf16* __restrict__ Wob,
                                                bf16* __restrict__ k1g,
                                                bf16* __restrict__ Wtb,
                                                float* __restrict__ u1,
                                                float* __restrict__ c1b) {
    __shared__ float tile[64][65];
    const int bid = blockIdx.x;
    const int tid = threadIdx.x;
    if (bid < 16384) {  // x cast
        const int i = (bid * 256 + tid) * 4;
        const float4 a = *(const float4*)(x + i);
        bf16x4 o;
        o[0] = (__bf16)a.x; o[1] = (__bf16)a.y; o[2] = (__bf16)a.z; o[3] = (__bf16)a.w;
        *(bf16x4*)(xb + i) = o;
        return;
    }
    if (bid < 18432) {  // Wo cast / k1g = k1 * g cast
        const int b2 = bid - 16384;
        const int sel = b2 >> 10;
        const int bb = b2 & 1023;
        const float* s = sel ? k1w : Wo;
        bf16* d = sel ? k1g : Wob;
        const int i = (bb * 256 + tid) * 4;
        float4 a = *(const float4*)(s + i);
        if (sel) {
            const float4 g4 = *(const float4*)(lng + (i & (DD - 1)));
            a.x *= g4.x; a.y *= g4.y; a.z *= g4.z; a.w *= g4.w;
        }
        bf16x4 o;
        o[0] = (__bf16)a.x; o[1] = (__bf16)a.y; o[2] = (__bf16)a.z; o[3] = (__bf16)a.w;
        *(bf16x4*)(d + i) = o;
        return;
    }
    if (bid < 19200) {  // transpose-cast Wq/Wk/Wv
        const int t = bid - 18432;
        const int tz = t >> 8;
        const int tb_ = t & 255;
        const float* in = (tz == 0) ? Wq : (tz == 1) ? Wk : Wv;
        bf16* out = Wtb + ((size_t)tz << 20);
        const int r0 = (tb_ >> 4) * 64, c0 = (tb_ & 15) * 64;
        const int lr = tid >> 4;
        const int lc = (tid & 15) * 4;
#pragma unroll
        for (int rr = 0; rr < 4; rr++) {
            const int row = lr + rr * 16;
            const float4 v = *(const float4*)(in + (size_t)(r0 + row) * DD + c0 + lc);
            tile[row][lc] = v.x; tile[row][lc + 1] = v.y;
            tile[row][lc + 2] = v.z; tile[row][lc + 3] = v.w;
        }
        __syncthreads();
#pragma unroll
        for (int rr = 0; rr < 4; rr++) {
            const int row = lr + rr * 16;
            bf16x4 o;
            o[0] = (__bf16)tile[lc + 0][row];
            o[1] = (__bf16)tile[lc + 1][row];
            o[2] = (__bf16)tile[lc + 2][row];
            o[3] = (__bf16)tile[lc + 3][row];
            *(bf16x4*)(out + (size_t)(c0 + row) * DD + r0 + lc) = o;
        }
        return;
    }
    // prep_vec
    const int pv = bid - 19200;
    const int lane = tid & 63, wave = tid >> 6;
    const int n = pv * 4 + wave;
    const float* row = k1w + (size_t)n * DD + lane * 16;
    float su = 0.f, sb = 0.f;
#pragma unroll
    for (int q = 0; q < 4; q++) {
        const float4 a = *(const float4*)(row + q * 4);
        const float4 g4 = *(const float4*)(lng + lane * 16 + q * 4);
        const float4 b4 = *(const float4*)(lnb + lane * 16 + q * 4);
        su += a.x * g4.x + a.y * g4.y + a.z * g4.z + a.w * g4.w;
        sb += a.x * b4.x + a.y * b4.y + a.z * b4.z + a.w * b4.w;
    }
#pragma unroll
    for (int off = 32; off > 0; off >>= 1) {
        su += __shfl_xor(su, off);
        sb += __shfl_xor(sb, off);
    }
    if (lane == 0) {
        u1[n] = su;
        c1b[n] = sb + k1b[n];
    }
}

// ---------------- paired tiny 1024^3 GEMMs: z=0 -> Gt, z=1 -> W2 ----------------
__global__ __launch_bounds__(256) void gemm_pair(const bf16* __restrict__ A0,
                                                 const bf16* __restrict__ W0,
                                                 bf16* __restrict__ O0,
                                                 const bf16* __restrict__ A1,
                                                 const bf16* __restrict__ W1,
                                                 bf16* __restrict__ O1) {
    const bf16* A = blockIdx.z ? A1 : A0;
    const bf16* W = blockIdx.z ? W1 : W0;
    bf16* O = blockIdx.z ? O1 : O0;
    __shared__ bf16 As[128 * BK];
    __shared__ bf16 Bs[128 * BK];
    const int tid = threadIdx.x;
    const int lane = tid & 63;
    const int wave = tid >> 6;
    const int wm = wave & 1;
    const int wn = wave >> 1;
    const int m0 = blockIdx.y * 128;
    const int n0 = blockIdx.x * 128;

    const int c = wave * 64 + lane;
    const int ar = c >> 2;
    const int ac = (c & 3) << 3;
    char* AsB = (char*)As;
    char* BsB = (char*)Bs;
    const int lr = lane & 15;
    const int lk = (lane >> 4) << 3;

    f32x4 acc[4][4] = {};

    for (int kt = 0; kt < DD; kt += BK) {
        const bf16* ga0 = A + (size_t)(m0 + ar) * DD + kt + ac;
        const bf16* gb0 = W + (size_t)(n0 + ar) * DD + kt + ac;
        GLOAD_LDS16(ga0, AsB + wave * 1024);
        GLOAD_LDS16(ga0 + (size_t)64 * DD, AsB + 4096 + wave * 1024);
        GLOAD_LDS16(gb0, BsB + wave * 1024);
        GLOAD_LDS16(gb0 + (size_t)64 * DD, BsB + 4096 + wave * 1024);
        __syncthreads();

        bf16x8 af[4], bfr[4];
#pragma unroll
        for (int i = 0; i < 4; i++)
            af[i] = *(const bf16x8*)&As[(wm * 64 + i * 16 + lr) * BK + lk];
#pragma unroll
        for (int j = 0; j < 4; j++)
            bfr[j] = *(const bf16x8*)&Bs[(wn * 64 + j * 16 + lr) * BK + lk];
#pragma unroll
        for (int i = 0; i < 4; i++)
#pragma unroll
            for (int j = 0; j < 4; j++)
                acc[i][j] = __builtin_amdgcn_mfma_f32_16x16x32_bf16(af[i], bfr[j], acc[i][j], 0, 0, 0);
        __syncthreads();
    }

#pragma unroll
    for (int i = 0; i < 4; i++) {
        const int row = m0 + wm * 64 + i * 16 + ((lane >> 4) << 2);
#pragma unroll
        for (int j = 0; j < 4; j++) {
            const int col = n0 + wn * 64 + j * 16 + (lane & 15);
#pragma unroll
            for (int rr = 0; rr < 4; rr++)
                O[(size_t)(row + rr) * DD + col] = (__bf16)acc[i][j][rr];
        }
    }
}

// ---------------- merged U / Vt2 GEMM: 256x128 tiles, 512 threads, flat grid 1024 ----------------
__global__ __launch_bounds__(512) void gemm_uv(const bf16* __restrict__ xb,
                                               const bf16* __restrict__ Gt,
                                               const bf16* __restrict__ W2,
                                               bf16* __restrict__ Ub,
                                               bf16* __restrict__ Vt2) {
    __shared__ bf16 As[256 * BK];
    __shared__ bf16 Bs[128 * BK];
    int id = blockIdx.x;
    const bf16* A;
    const bf16* W;
    bf16* O;
    int m0, n0, ldo;
    if (id < 512) {
        A = xb; W = Gt; O = Ub;
        m0 = (id & 63) * 256; n0 = (id >> 6) * 128; ldo = DD;
    } else {
        id -= 512;
        A = W2; W = xb; O = Vt2;
        m0 = (id >> 7) * 256; n0 = (id & 127) * 128; ldo = 4 * SS;
    }
    const int tid = threadIdx.x;
    const int lane = tid & 63;
    const int wave = tid >> 6;
    const int wm = wave & 3;
    const int wn = wave >> 2;

    const int ar = tid >> 2;
    const int ac = (tid & 3) << 3;
    char* AsB = (char*)As;
    char* BsB = (char*)Bs;
    const int lr = lane & 15;
    const int lk = (lane >> 4) << 3;

    f32x4 acc[4][4] = {};

    for (int kt = 0; kt < DD; kt += BK) {
        const bf16* ga0 = A + (size_t)(m0 + ar) * DD + kt + ac;
        const bf16* gb0 = W + (size_t)(n0 + ar) * DD + kt + ac;
        GLOAD_LDS16(ga0, AsB + wave * 1024);
        GLOAD_LDS16(ga0 + (size_t)128 * DD, AsB + 8192 + wave * 1024);
        GLOAD_LDS16(gb0, BsB + wave * 1024);
        __syncthreads();

        bf16x8 af[4], bfr[4];
#pragma unroll
        for (int i = 0; i < 4; i++)
            af[i] = *(const bf16x8*)&As[(wm * 64 + i * 16 + lr) * BK + lk];
#pragma unroll
        for (int j = 0; j < 4; j++)
            bfr[j] = *(const bf16x8*)&Bs[(wn * 64 + j * 16 + lr) * BK + lk];
#pragma unroll
        for (int i = 0; i < 4; i++)
#pragma unroll
            for (int j = 0; j < 4; j++)
                acc[i][j] = __builtin_amdgcn_mfma_f32_16x16x32_bf16(af[i], bfr[j], acc[i][j], 0, 0, 0);
        __syncthreads();
    }

#pragma unroll
    for (int i = 0; i < 4; i++) {
        const int row = m0 + wm * 64 + i * 16 + ((lane >> 4) << 2);
#pragma unroll
        for (int j = 0; j < 4; j++) {
            const int col = n0 + wn * 64 + j * 16 + (lane & 15);
#pragma unroll
            for (int rr = 0; rr < 4; rr++)
                O[(size_t)(row + rr) * ldo + col] = (__bf16)acc[i][j][rr];
        }
    }
}

// ---------------- k1 GEMM, folded LN1 + in-block row stats, partial-only output ------
__global__ __launch_bounds__(512) void gemm_k1(const bf16* __restrict__ T,
                                               const bf16* __restrict__ k1g,
                                               const float* __restrict__ part_t,
                                               const float* __restrict__ u1,
                                               const float* __restrict__ c1b,
                                               const float* __restrict__ lng,
                                               const float* __restrict__ k2w,
                                               float* __restrict__ part_h) {
    __shared__ bf16 As[256 * BK];
    __shared__ bf16 Bs[128 * BK];
    __shared__ float lmu[256], lrs[256];
    const int m0 = blockIdx.x * 256;
    const int n0 = blockIdx.y * 128;
    const int tid = threadIdx.x;
    const int lane = tid & 63;
    const int wave = tid >> 6;
    const int wm = wave & 3;
    const int wn = wave >> 2;

    const int ar = tid >> 2;
    const int ac = (tid & 3) << 3;
    char* AsB = (char*)As;
    char* BsB = (char*)Bs;
    const int lr = lane & 15;
    const int lk = (lane >> 4) << 3;

    // per-row LN1 stats from part_t (exact)
    if (tid < 256) {
        const float* p = part_t + (size_t)(m0 + tid) * 32;
        float s1 = 0.f, s2 = 0.f;
#pragma unroll
        for (int s = 0; s < 8; s++) {
            const float4 v = *(const float4*)(p + s * 4);
            s1 += v.x + v.z;
            s2 += v.y + v.w;
        }
        const float m = s1 * (1.f / DD);
        lmu[tid] = m;
        lrs[tid] = rsqrtf(s2 * (1.f / DD) - m * m + LN_EPS);
    }

    f32x4 acc[4][4] = {};

    for (int kt = 0; kt < DD; kt += BK) {
        const bf16* ga0 = T + (size_t)(m0 + ar) * DD + kt + ac;
        const bf16* gb0 = k1g + (size_t)(n0 + ar) * DD + kt + ac;
        GLOAD_LDS16(ga0, AsB + wave * 1024);
        GLOAD_LDS16(ga0 + (size_t)128 * DD, AsB + 8192 + wave * 1024);
        GLOAD_LDS16(gb0, BsB + wave * 1024);
        __syncthreads();

        bf16x8 af[4], bfr[4];
#pragma unroll
        for (int i = 0; i < 4; i++)
            af[i] = *(const bf16x8*)&As[(wm * 64 + i * 16 + lr) * BK + lk];
#pragma unroll
        for (int j = 0; j < 4; j++)
            bfr[j] = *(const bf16x8*)&Bs[(wn * 64 + j * 16 + lr) * BK + lk];
#pragma unroll
        for (int i = 0; i < 4; i++)
#pragma unroll
            for (int j = 0; j < 4; j++)
                acc[i][j] = __builtin_amdgcn_mfma_f32_16x16x32_bf16(af[i], bfr[j], acc[i][j], 0, 0, 0);
        __syncthreads();
    }

    float u1v[4], cbv[4], ugv[4];
#pragma unroll
    for (int j = 0; j < 4; j++) {
        const int col = n0 + wn * 64 + j * 16 + (lane & 15);
        u1v[j] = u1[col];
        cbv[j] = c1b[col];
        ugv[j] = lng[col] * k2w[col];
    }
    const int strip = blockIdx.y * 2 + wn;
#pragma unroll
    for (int i = 0; i < 4; i++) {
#pragma unroll
        for (int rr = 0; rr < 4; rr++) {
            const int lrow = wm * 64 + i * 16 + ((lane >> 4) << 2) + rr;
            const int row = m0 + lrow;
            const float mr = lmu[lrow], rs = lrs[lrow];
            float s1 = 0.f, s2 = 0.f, s3 = 0.f;
#pragma unroll
            for (int j = 0; j < 4; j++) {
                const float v = rs * (acc[i][j][rr] - mr * u1v[j]) + cbv[j];
                const float h = fmaxf(v, 0.f);
                s1 += h; s2 += h * h; s3 += h * ugv[j];
            }
#pragma unroll
            for (int off = 8; off > 0; off >>= 1) {
                s1 += __shfl_xor(s1, off);
                s2 += __shfl_xor(s2, off);
                s3 += __shfl_xor(s3, off);
            }
            if ((lane & 15) == 0) {
                float* p = part_h + (size_t)row * 48 + strip * 3;
                p[0] = s1; p[1] = s2; p[2] = s3;
            }
        }
    }
}

// ---------------- attention pass A1: raw banded scores S = U @ x_band^T ----------------
// grid (x = 128 m-tiles, y = 3 band blocks): U-strip sharers on same XCD
__global__ __launch_bounds__(256) void attn_s_mfma(const bf16* __restrict__ U,
                                                   const bf16* __restrict__ X,
                                                   float* __restrict__ S) {
    __shared__ bf16 As[128 * BK];
    __shared__ bf16 Bs[128 * BK];
    const int tid = threadIdx.x;
    const int lane = tid & 63;
    const int wave = tid >> 6;
    const int wm = wave & 1;
    const int wn = wave >> 1;
    const int t = blockIdx.x;
    const int nb = blockIdx.y;
    const int m0 = t * 128;
    const long w0 = (long)t * 128 - 128 + (long)nb * 128;  // OOB -> bf16 guard buffers, masked in softmax

    const int c = wave * 64 + lane;
    const int ar = c >> 2;
    const int ac = (c & 3) << 3;
    char* AsB = (char*)As;
    char* BsB = (char*)Bs;
    const int lr = lane & 15;
    const int lk = (lane >> 4) << 3;

    f32x4 acc[4][4] = {};

    for (int kt = 0; kt < DD; kt += BK) {
        const bf16* ga0 = U + (size_t)(m0 + ar) * DD + kt + ac;
        const bf16* gb0 = X + (w0 + ar) * DD + kt + ac;
        GLOAD_LDS16(ga0, AsB + wave * 1024);
        GLOAD_LDS16(ga0 + (size_t)64 * DD, AsB + 4096 + wave * 1024);
        GLOAD_LDS16(gb0, BsB + wave * 1024);
        GLOAD_LDS16(gb0 + (size_t)64 * DD, BsB + 4096 + wave * 1024);
        __syncthreads();

        bf16x8 af[4], bfr[4];
#pragma unroll
        for (int i = 0; i < 4; i++)
            af[i] = *(const bf16x8*)&As[(wm * 64 + i * 16 + lr) * BK + lk];
#pragma unroll
        for (int j = 0; j < 4; j++)
            bfr[j] = *(const bf16x8*)&Bs[(wn * 64 + j * 16 + lr) * BK + lk];
#pragma unroll
        for (int i = 0; i < 4; i++)
#pragma unroll
            for (int j = 0; j < 4; j++)
                acc[i][j] = __builtin_amdgcn_mfma_f32_16x16x32_bf16(af[i], bfr[j], acc[i][j], 0, 0, 0);
        __syncthreads();
    }

#pragma unroll
    for (int i = 0; i < 4; i++) {
        const int row = m0 + wm * 64 + i * 16 + ((lane >> 4) << 2);
#pragma unroll
        for (int j = 0; j < 4; j++) {
            const int col = nb * 128 + wn * 64 + j * 16 + (lane & 15);
#pragma unroll
            for (int rr = 0; rr < 4; rr++)
                S[(size_t)(row + rr) * BAND + col] = acc[i][j][rr];
        }
    }
}

// ---------------- attention pass A2: masked softmax, normalized bf16 P ----------------
__global__ __launch_bounds__(256) void attn_softmax(const float* __restrict__ S,
                                                    bf16* __restrict__ P) {
    const int wave = threadIdx.x >> 6;
    const int lane = threadIdx.x & 63;
    const int g = blockIdx.x * 4 + wave;
    const int i = g & (SS - 1);
    const int j_start = ((i >> 7) << 7) - 128;
    const float scale = 0.03125f;
    float s[6];
    float m = -INFINITY;
#pragma unroll
    for (int t = 0; t < 6; t++) {
        const int jj = lane + t * 64;
        const int j = j_start + jj;
        const int dj = j - i;
        const bool valid = (j >= 0) && (j < SS) && (dj != 0) && (dj <= AP) && (dj >= -AP);
        const float v = S[(size_t)g * BAND + jj] * scale;
        s[t] = valid ? v : -INFINITY;
        m = fmaxf(m, s[t]);
    }
#pragma unroll
    for (int off = 32; off > 0; off >>= 1) m = fmaxf(m, __shfl_xor(m, off));
    float l = 0.f;
#pragma unroll
    for (int t = 0; t < 6; t++) {
        s[t] = __expf(s[t] - m);
        l += s[t];
    }
#pragma unroll
    for (int off = 32; off > 0; off >>= 1) l += __shfl_xor(l, off);
    const float inv = 1.f / l;
#pragma unroll
    for (int t = 0; t < 6; t++)
        P[(size_t)g * BAND + lane + t * 64] = (__bf16)(s[t] * inv);
}

// ---------------- attention pass B + residual + T row-partials ----------------
// 128x256 tiles, 512 threads, grid (x = 128 t, y = 4 n-blocks of 256)
__global__ __launch_bounds__(512) void attn_pv_mfma(const bf16* __restrict__ P,
                                                    const bf16* __restrict__ Vt,
                                                    const bf16* __restrict__ xres,
                                                    bf16* __restrict__ T,
                                                    float* __restrict__ part_t) {
    __shared__ bf16 As[128 * BK];   // P tile   8KB
    __shared__ bf16 Bs[256 * BK];   // Vt tile 16KB
    const int tid = threadIdx.x;
    const int lane = tid & 63;
    const int wave = tid >> 6;     // 0..7
    const int wm = wave & 1;       // 2 m-strips of 64
    const int wn = wave >> 1;      // 4 n-strips of 64
    const int t = blockIdx.x;
    const int m0 = t * 128;
    const int n0 = blockIdx.y * 256;
    const bf16* Wb = Vt + (long)t * 128 - 128;

    const int ar = tid >> 2;           // 0..127
    const int ac = (tid & 3) << 3;
    char* AsB = (char*)As;
    char* BsB = (char*)Bs;
    const int lr = lane & 15;
    const int lk = (lane >> 4) << 3;

    f32x4 acc[4][4] = {};

    for (int kt = 0; kt < BAND; kt += BK) {
        const bf16* ga0 = P + (size_t)(m0 + ar) * BAND + kt + ac;
        const bf16* gb0 = Wb + (size_t)(n0 + ar) * (4 * SS) + kt + ac;
        GLOAD_LDS16(ga0, AsB + wave * 1024);
        GLOAD_LDS16(gb0, BsB + wave * 1024);
        GLOAD_LDS16(gb0 + (size_t)128 * (4 * SS), BsB + 8192 + wave * 1024);
        __syncthreads();

        bf16x8 af[4], bfr[4];
#pragma unroll
        for (int i = 0; i < 4; i++)
            af[i] = *(const bf16x8*)&As[(wm * 64 + i * 16 + lr) * BK + lk];
#pragma unroll
        for (int j = 0; j < 4; j++)
            bfr[j] = *(const bf16x8*)&Bs[(wn * 64 + j * 16 + lr) * BK + lk];
#pragma unroll
        for (int i = 0; i < 4; i++)
#pragma unroll
            for (int j = 0; j < 4; j++)
                acc[i][j] = __builtin_amdgcn_mfma_f32_16x16x32_bf16(af[i], bfr[j], acc[i][j], 0, 0, 0);
        __syncthreads();
    }

    const int strip = blockIdx.y * 4 + wn;  // 16 strips of 64 cols
#pragma unroll
    for (int i = 0; i < 4; i++) {
#pragma unroll
        for (int rr = 0; rr < 4; rr++) {
            const int row = m0 + wm * 64 + i * 16 + ((lane >> 4) << 2) + rr;
            float s1 = 0.f, s2 = 0.f;
#pragma unroll
            for (int j = 0; j < 4; j++) {
                const int col = n0 + wn * 64 + j * 16 + (lane & 15);
                const size_t idx = (size_t)row * DD + col;
                const __bf16 tv_b = (__bf16)(acc[i][j][rr] + (float)xres[idx]);
                T[idx] = tv_b;
                const float tv = (float)tv_b;
                s1 += tv; s2 += tv * tv;
            }
#pragma unroll
            for (int off = 8; off > 0; off >>= 1) {
                s1 += __shfl_xor(s1, off);
                s2 += __shfl_xor(s2, off);
            }
            if ((lane & 15) == 0) {
                float2 st; st.x = s1; st.y = s2;
                *(float2*)(part_t + (size_t)row * 32 + strip * 2) = st;
            }
        }
    }
}

// ---------------- reduce H partials -> sigmoid head ----------------
__global__ __launch_bounds__(256) void ln_k2_p(const float* __restrict__ part_h,
                                               const float* __restrict__ g,
                                               const float* __restrict__ bta,
                                               const float* __restrict__ w2,
                                               const float* __restrict__ b2,
                                               float* __restrict__ out) {
    __shared__ float red[256], red2[256];
    const int tid = threadIdx.x;
    const float4 g4 = *(const float4*)(g + tid * 4);
    const float4 w4 = *(const float4*)(w2 + tid * 4);
    const float4 b4 = *(const float4*)(bta + tid * 4);
    red[tid] = g4.x * w4.x + g4.y * w4.y + g4.z * w4.z + g4.w * w4.w;
    red2[tid] = b4.x * w4.x + b4.y * w4.y + b4.z * w4.z + b4.w * w4.w;
    __syncthreads();
    for (int s = 128; s > 0; s >>= 1) {
        if (tid < s) { red[tid] += red[tid + s]; red2[tid] += red2[tid + s]; }
        __syncthreads();
    }
    const float sum_u = red[0];
    const float sum_bw = red2[0];

    const int r = blockIdx.x * 256 + tid;
    const float* p = part_h + (size_t)r * 48;
    float s1 = 0.f, s2 = 0.f, s3 = 0.f;
#pragma unroll
    for (int s = 0; s < 16; s++) {
        s1 += p[s * 3 + 0];
        s2 += p[s * 3 + 1];
        s3 += p[s * 3 + 2];
    }
    const float m = s1 * (1.f / DD);
    const float var = s2 * (1.f / DD) - m * m;
    const float rs = rsqrtf(var + LN_EPS);
    const float z = rs * (s3 - m * sum_u) + sum_bw + b2[0];
    out[r] = 1.f / (1.f + __expf(-z));
}

extern "C" void kernel_launch(void* const* d_in, const int* in_sizes, int n_in,
                              void* d_out, int out_size, void* d_ws, size_t ws_size,
                              hipStream_t stream) {
    const float* x   = (const float*)d_in[0];
    const float* Wq  = (const float*)d_in[1];
    const float* Wk  = (const float*)d_in[2];
    const float* Wv  = (const float*)d_in[3];
    const float* Wo  = (const float*)d_in[4];
    const float* k1w = (const float*)d_in[5];
    const float* k1b = (const float*)d_in[6];
    const float* k2w = (const float*)d_in[7];
    const float* k2b = (const float*)d_in[8];
    const float* lng = (const float*)d_in[9];
    const float* lnb = (const float*)d_in[10];
    float* out = (float*)d_out;

    const int N = 4 * SS;  // 16384 rows
    char* ws = (char*)d_ws;
    // layout (MB). Banded passes read +/-256KB around xb and Vt2 -> neighbors
    // must be valid bf16 (Ub | xb | Vt2 | P). Masked / zero-weighted.
    bf16*  Ub   = (bf16*)(ws);                          //   0..32
    bf16*  xb   = (bf16*)(ws + ((size_t)32  << 20));    //  32..64
    bf16*  Vt2  = (bf16*)(ws + ((size_t)64  << 20));    //  64..96  [1024][16384]
    bf16*  P    = (bf16*)(ws + ((size_t)96  << 20));    //  96..108
    float* S    = (float*)(ws + ((size_t)108 << 20));   // 108..132
    bf16*  T    = (bf16*)(ws + ((size_t)164 << 20));    // 164..196
    bf16*  Wtb  = (bf16*)(ws + ((size_t)196 << 20));    // 196..202: Wq^T, Wk^T, Wv^T
    bf16*  Wqtb = Wtb;
    bf16*  Wktb = Wqtb + (1 << 20);
    bf16*  Wvtb = Wktb + (1 << 20);
    bf16*  Wob  = Wvtb + (1 << 20);                     // 202..204
    bf16*  k1g  = Wob  + (1 << 20);                     // 204..206
    bf16*  Gtb  = k1g  + (1 << 20);                     // 206..208
    bf16*  W2b  = Gtb  + (1 << 20);                     // 208..210
    float* u1     = (float*)(ws + ((size_t)210 << 20)); // 4 KB
    float* c1b    = u1 + DD;                            // 4 KB
    float* part_t = (float*)(ws + ((size_t)211 << 20)); // 211..213: [16384][16][2]
    float* part_h = (float*)(ws + ((size_t)214 << 20)); // 214..217: [16384][16][3]

    dim3 tb(256);

    prep_all<<<19456, tb, 0, stream>>>(x, Wq, Wk, Wv, Wo, k1w, k1b, lng, lnb,
                                       xb, Wob, k1g, Wtb, u1, c1b);

    // Gt = Wk^T @ Wq (bt-layout)  |  W2 = Wo @ Wv (bt on Wv^T)
    gemm_pair<<<dim3(8, 8, 2), tb, 0, stream>>>(Wktb, Wqtb, Gtb, Wob, Wvtb, W2b);

    gemm_uv<<<1024, dim3(512), 0, stream>>>(xb, Gtb, W2b, Ub, Vt2);

    attn_s_mfma<<<dim3(N / 128, 3), tb, 0, stream>>>(Ub, xb, S);
    attn_softmax<<<N / 4, tb, 0, stream>>>(S, P);
    attn_pv_mfma<<<dim3(N / 128, 4), dim3(512), 0, stream>>>(P, Vt2, xb, T, part_t);

    gemm_k1<<<dim3(64, 8), dim3(512), 0, stream>>>(T, k1g, part_t, u1, c1b, lng, k2w, part_h);
    ln_k2_p<<<N / 256, tb, 0, stream>>>(part_h, lng, lnb, k2w, k2b, out);
}